// Round 3
// baseline (2755.876 us; speedup 1.0000x reference)
//
#include <hip/hip_runtime.h>

#define N_ 4096
#define DIM_ 512
#define H_ 8
#define DH_ 64
#define M_ 266
#define NT_ 16384
#define BH_ 32

#define NORMC 0.3535533905932738f   // 64^-0.25
#define RATIOC 0.06131393394849658f // 266^-0.5
#define EPSK 1e-4f
#define DIAGC 0.0625f               // 0.5 * normalizer^2

// ---- ws layout ----
// [int flag][pad to 16B: floats 1..3][ctx 544768 f][ksum 8512 f][part 512 f][kmax 32 f]
// then canonical bf16 inputs, then Q/K/V bf16. attn aliases K.
#define CTXF 4ul
#define KSUMF (CTXF + 544768ul)
#define PARTF (KSUMF + 8512ul)
#define KMAXF (PARTF + 512ul)
#define SMALLF (KMAXF + 32ul)              // 553828 floats
#define CANON_BYTE (SMALLF * 4ul)          // 2,215,312 (16B aligned)
#define XN 8388608ul
#define WN 262144ul
#define BON 512ul
#define PJN 17024ul

__device__ __forceinline__ float bfu(unsigned short u) {
  union { unsigned int i; float f; } x; x.i = ((unsigned int)u) << 16; return x.f;
}
__device__ __forceinline__ unsigned short f2bf(float f) {
  union { float f; unsigned int i; } u; u.f = f;
  unsigned int r = u.i + 0x7fffu + ((u.i >> 16) & 1u);
  return (unsigned short)(r >> 16);
}

// ---------------- dtype sniffer: bf16 (flag=0) vs fp32 (flag=1) ----------------
__global__ void detect_kernel(const unsigned short* __restrict__ x, int* __restrict__ flag) {
  __shared__ int cnt;
  if (threadIdx.x == 0) cnt = 0;
  __syncthreads();
  int bad = 0;
  for (int i = threadIdx.x; i < 4096; i += 256) {
    const unsigned short u = x[2 * i];   // even u16: bf16 value OR fp32 low-mantissa garbage
    const int e = (u >> 7) & 0xFF;
    const int sane = (u == 0u || u == 0x8000u || (e >= 90 && e <= 150));
    bad += !sane;
  }
  atomicAdd(&cnt, bad);
  __syncthreads();
  if (threadIdx.x == 0) *flag = (cnt > 1600) ? 1 : 0;
}

// ---------------- canonicalize any input to bf16 u16 ----------------
__global__ void canon_kernel(const void* __restrict__ src, unsigned short* __restrict__ dst,
                             int n, const int* __restrict__ flag) {
  const int f = *flag;
  int i = blockIdx.x * 256 + threadIdx.x;
  const int stride = gridDim.x * 256;
  if (f) {
    const float* s = (const float*)src;
    for (; i < n; i += stride) dst[i] = f2bf(s[i]);
  } else {
    const unsigned short* s = (const unsigned short*)src;
    for (; i < n; i += stride) dst[i] = s[i];
  }
}

// ---------------- QKV projection ----------------
__global__ __launch_bounds__(256) void qkv_gemm(
    const unsigned short* __restrict__ x, const unsigned short* __restrict__ Wq,
    const unsigned short* __restrict__ Wk, const unsigned short* __restrict__ Wv,
    unsigned short* __restrict__ qkv) {
  const unsigned short* W = (blockIdx.z == 0) ? Wq : (blockIdx.z == 1) ? Wk : Wv;
  unsigned short* outp = qkv + (size_t)blockIdx.z * XN;
  __shared__ float As[16][68];
  __shared__ float Bs[16][68];
  const int tid = threadIdx.x;
  const int tx = tid & 15, ty = tid >> 4;
  const int tm0 = blockIdx.x * 64, tn0 = blockIdx.y * 64;
  const int lr = tid >> 2, lc = (tid & 3) << 2;
  float acc[4][4] = {};
  for (int k0 = 0; k0 < DIM_; k0 += 16) {
    const ushort4 ua = *(const ushort4*)&x[(size_t)(tm0 + lr) * DIM_ + k0 + lc];
    const ushort4 ub = *(const ushort4*)&W[(size_t)(tn0 + lr) * DIM_ + k0 + lc];
    As[lc + 0][lr] = bfu(ua.x); As[lc + 1][lr] = bfu(ua.y);
    As[lc + 2][lr] = bfu(ua.z); As[lc + 3][lr] = bfu(ua.w);
    Bs[lc + 0][lr] = bfu(ub.x); Bs[lc + 1][lr] = bfu(ub.y);
    Bs[lc + 2][lr] = bfu(ub.z); Bs[lc + 3][lr] = bfu(ub.w);
    __syncthreads();
#pragma unroll
    for (int kk = 0; kk < 16; ++kk) {
      const float4 av = *(const float4*)&As[kk][ty * 4];
      const float4 bv = *(const float4*)&Bs[kk][tx * 4];
      acc[0][0] += av.x * bv.x; acc[0][1] += av.x * bv.y; acc[0][2] += av.x * bv.z; acc[0][3] += av.x * bv.w;
      acc[1][0] += av.y * bv.x; acc[1][1] += av.y * bv.y; acc[1][2] += av.y * bv.z; acc[1][3] += av.y * bv.w;
      acc[2][0] += av.z * bv.x; acc[2][1] += av.z * bv.y; acc[2][2] += av.z * bv.z; acc[2][3] += av.z * bv.w;
      acc[3][0] += av.w * bv.x; acc[3][1] += av.w * bv.y; acc[3][2] += av.w * bv.z; acc[3][3] += av.w * bv.w;
    }
    __syncthreads();
  }
#pragma unroll
  for (int i = 0; i < 4; ++i) {
    const int t = tm0 + ty * 4 + i;
    const int b = t >> 12, n = t & (N_ - 1);
#pragma unroll
    for (int j = 0; j < 4; ++j) {
      const int e = tn0 + tx * 4 + j;
      const int h = e >> 6, dh = e & 63;
      outp[(((size_t)(b * H_ + h)) * N_ + n) * DH_ + dh] = f2bf(acc[i][j]);
    }
  }
}

// ---------------- per-(b,h) max over (n,m) of td (key branch) ----------------
__global__ __launch_bounds__(256) void kmax_part_kernel(
    const unsigned short* __restrict__ kbuf, const unsigned short* __restrict__ proj,
    float* __restrict__ part) {
  __shared__ unsigned short pl[M_][66];  // 33-word row stride: conflict-free
  __shared__ float red[256];
  const int bh = blockIdx.x, ch = blockIdx.y, tid = threadIdx.x;
  for (int i = tid; i < M_ * DH_; i += 256) pl[i >> 6][i & 63] = proj[i];
  __syncthreads();
  const int n = ch * 256 + tid;
  const unsigned short* kr = kbuf + ((size_t)bh * N_ + n) * DH_;
  float kk[64];
#pragma unroll
  for (int i = 0; i < 16; ++i) {
    const ushort4 u = ((const ushort4*)kr)[i];
    kk[i * 4 + 0] = bfu(u.x); kk[i * 4 + 1] = bfu(u.y);
    kk[i * 4 + 2] = bfu(u.z); kk[i * 4 + 3] = bfu(u.w);
  }
  float mx = -3e38f;
  for (int m = 0; m < M_; ++m) {
    float s = 0.f;
#pragma unroll
    for (int d = 0; d < 64; ++d) s += kk[d] * bfu(pl[m][d]);
    mx = fmaxf(mx, s);
  }
  mx *= NORMC;
  red[tid] = mx;
  __syncthreads();
  for (int s = 128; s > 0; s >>= 1) {
    if (tid < s) red[tid] = fmaxf(red[tid], red[tid + s]);
    __syncthreads();
  }
  if (tid == 0) part[bh * 16 + ch] = red[0];
}

__global__ void kmax_reduce(const float* __restrict__ part, float* __restrict__ kmax) {
  const int t = threadIdx.x;
  if (t < BH_) {
    float m = part[t * 16];
    for (int i = 1; i < 16; ++i) m = fmaxf(m, part[t * 16 + i]);
    kmax[t] = m;
  }
}

__global__ void zero_kernel(float* __restrict__ p, int n) {
  int i = blockIdx.x * blockDim.x + threadIdx.x;
  const int stride = gridDim.x * blockDim.x;
  for (; i < n; i += stride) p[i] = 0.f;
}

// ---------------- context[m,d] += kp[n,m]*v[n,d]; ksum[m] += kp[n,m] ----------------
__global__ __launch_bounds__(256) void ctx_kernel(
    const unsigned short* __restrict__ kbuf, const unsigned short* __restrict__ vbuf,
    const unsigned short* __restrict__ proj, const float* __restrict__ kmaxv,
    float* __restrict__ ctx, float* __restrict__ ksum) {
  __shared__ unsigned short pl[M_][66];
  __shared__ float kl[4][64];
  __shared__ float vl[4][64];
  __shared__ float kp[4][M_];
  __shared__ float dg[4];
  const int tid = threadIdx.x;
  const int bh = blockIdx.x, ch = blockIdx.y;
  for (int i = tid; i < M_ * DH_; i += 256) pl[i >> 6][i & 63] = proj[i];
  const float km = kmaxv[bh];
  const int tm = tid & 15, tq = tid >> 4;
  float acc[17][4];
  float ksa[17];
#pragma unroll
  for (int ii = 0; ii < 17; ++ii) {
    acc[ii][0] = acc[ii][1] = acc[ii][2] = acc[ii][3] = 0.f;
    ksa[ii] = 0.f;
  }
  const unsigned short* kb = kbuf + (size_t)bh * N_ * DH_;
  const unsigned short* vb = vbuf + (size_t)bh * N_ * DH_;
  __syncthreads();
  for (int n0 = ch * 512; n0 < ch * 512 + 512; n0 += 4) {
    kl[tid >> 6][tid & 63] = bfu(kb[(size_t)n0 * DH_ + tid]);
    vl[tid >> 6][tid & 63] = bfu(vb[(size_t)n0 * DH_ + tid]);
    __syncthreads();
    if (tid < 4) {
      float s = 0.f;
#pragma unroll
      for (int d = 0; d < 64; ++d) s += kl[tid][d] * kl[tid][d];
      dg[tid] = s * DIAGC;
    }
    for (int m = tid; m < M_; m += 256) {
      float t0 = 0.f, t1 = 0.f, t2 = 0.f, t3 = 0.f;
#pragma unroll
      for (int d = 0; d < 64; ++d) {
        const float p = bfu(pl[m][d]);
        t0 += p * kl[0][d]; t1 += p * kl[1][d]; t2 += p * kl[2][d]; t3 += p * kl[3][d];
      }
      kp[0][m] = t0 * NORMC; kp[1][m] = t1 * NORMC;
      kp[2][m] = t2 * NORMC; kp[3][m] = t3 * NORMC;
    }
    __syncthreads();
#pragma unroll
    for (int j = 0; j < 4; ++j)
      for (int m = tid; m < M_; m += 256)
        kp[j][m] = RATIOC * (__expf(kp[j][m] - dg[j] - km) + EPSK);
    __syncthreads();
    const float4 vv0 = *(const float4*)&vl[0][tq * 4];
    const float4 vv1 = *(const float4*)&vl[1][tq * 4];
    const float4 vv2 = *(const float4*)&vl[2][tq * 4];
    const float4 vv3 = *(const float4*)&vl[3][tq * 4];
#pragma unroll
    for (int ii = 0; ii < 17; ++ii) {
      const int m = tm + ii * 16;
      if (m < M_) {
        const float k0 = kp[0][m], k1 = kp[1][m], k2 = kp[2][m], k3 = kp[3][m];
        acc[ii][0] += k0 * vv0.x + k1 * vv1.x + k2 * vv2.x + k3 * vv3.x;
        acc[ii][1] += k0 * vv0.y + k1 * vv1.y + k2 * vv2.y + k3 * vv3.y;
        acc[ii][2] += k0 * vv0.z + k1 * vv1.z + k2 * vv2.z + k3 * vv3.z;
        acc[ii][3] += k0 * vv0.w + k1 * vv1.w + k2 * vv2.w + k3 * vv3.w;
        if (tq == 0) ksa[ii] += k0 + k1 + k2 + k3;
      }
    }
    __syncthreads();
  }
  for (int ii = 0; ii < 17; ++ii) {
    const int m = tm + ii * 16;
    if (m < M_) {
      float* cp = ctx + ((size_t)bh * M_ + m) * DH_ + tq * 4;
      atomicAdd(cp + 0, acc[ii][0]);
      atomicAdd(cp + 1, acc[ii][1]);
      atomicAdd(cp + 2, acc[ii][2]);
      atomicAdd(cp + 3, acc[ii][3]);
      if (tq == 0) atomicAdd(&ksum[bh * M_ + m], ksa[ii]);
    }
  }
}

// ---------------- per-token: qp, d_inv, out = ctx^T qp * d_inv ----------------
__global__ __launch_bounds__(256) void out_kernel(
    const unsigned short* __restrict__ qbuf, const unsigned short* __restrict__ proj,
    const float* __restrict__ ctx, const float* __restrict__ ksum,
    unsigned short* __restrict__ attn) {
  __shared__ unsigned short ctxs[M_][66];
  __shared__ float qs[16][DH_];
  __shared__ float qp[16][M_ + 2];
  __shared__ float ksums[M_];
  __shared__ float rmax[16], diag[16], dinv[16];
  const int tid = threadIdx.x;
  const int bh = blockIdx.x;
  const int r0 = blockIdx.y * 16;
  for (int i = tid; i < M_ * DH_; i += 256)
    ctxs[i >> 6][i & 63] = f2bf(ctx[(size_t)bh * M_ * DH_ + i]);
  for (int i = tid; i < M_; i += 256) ksums[i] = ksum[bh * M_ + i];
  for (int i = tid; i < 16 * DH_; i += 256)
    qs[i >> 6][i & 63] = bfu(qbuf[((size_t)bh * N_ + r0 + (i >> 6)) * DH_ + (i & 63)]);
  __syncthreads();
  if (tid < 16) {
    float s = 0.f;
#pragma unroll
    for (int d = 0; d < 64; ++d) s += qs[tid][d] * qs[tid][d];
    diag[tid] = s * DIAGC;
  }
  for (int m = tid; m < M_; m += 256) {
    const uint4* pm = (const uint4*)(proj + (size_t)m * DH_);
    float td_[16];
#pragma unroll
    for (int r = 0; r < 16; ++r) td_[r] = 0.f;
#pragma unroll
    for (int c = 0; c < 8; ++c) {
      const uint4 u = pm[c];
      const int d = c * 8;
      const float p0 = bfu((unsigned short)(u.x & 0xffffu)), p1 = bfu((unsigned short)(u.x >> 16));
      const float p2 = bfu((unsigned short)(u.y & 0xffffu)), p3 = bfu((unsigned short)(u.y >> 16));
      const float p4 = bfu((unsigned short)(u.z & 0xffffu)), p5 = bfu((unsigned short)(u.z >> 16));
      const float p6 = bfu((unsigned short)(u.w & 0xffffu)), p7 = bfu((unsigned short)(u.w >> 16));
#pragma unroll
      for (int r = 0; r < 16; ++r) {
        td_[r] += qs[r][d] * p0 + qs[r][d + 1] * p1 + qs[r][d + 2] * p2 + qs[r][d + 3] * p3 +
                  qs[r][d + 4] * p4 + qs[r][d + 5] * p5 + qs[r][d + 6] * p6 + qs[r][d + 7] * p7;
      }
    }
#pragma unroll
    for (int r = 0; r < 16; ++r) qp[r][m] = NORMC * td_[r];
  }
  __syncthreads();
  if (tid < 16) {
    float mx = -3e38f;
    for (int m = 0; m < M_; ++m) mx = fmaxf(mx, qp[tid][m]);
    rmax[tid] = mx;
  }
  __syncthreads();
  for (int r = 0; r < 16; ++r)
    for (int m = tid; m < M_; m += 256)
      qp[r][m] = RATIOC * (__expf(qp[r][m] - diag[r] - rmax[r]) + EPSK);
  __syncthreads();
  if (tid < 16) {
    float s = 0.f;
    for (int m = 0; m < M_; ++m) s += qp[tid][m] * ksums[m];
    dinv[tid] = 1.f / s;
  }
  __syncthreads();
  const int d = tid & 63;
  const int rg = tid >> 6;
  float o0 = 0.f, o1 = 0.f, o2 = 0.f, o3 = 0.f;
  for (int m = 0; m < M_; ++m) {
    const float cv = bfu(ctxs[m][d]);
    o0 += qp[rg][m] * cv;
    o1 += qp[rg + 4][m] * cv;
    o2 += qp[rg + 8][m] * cv;
    o3 += qp[rg + 12][m] * cv;
  }
  const int b = bh >> 3, h = bh & 7;
  attn[((size_t)b * N_ + r0 + rg) * DIM_ + h * DH_ + d] = f2bf(o0 * dinv[rg]);
  attn[((size_t)b * N_ + r0 + rg + 4) * DIM_ + h * DH_ + d] = f2bf(o1 * dinv[rg + 4]);
  attn[((size_t)b * N_ + r0 + rg + 8) * DIM_ + h * DH_ + d] = f2bf(o2 * dinv[rg + 8]);
  attn[((size_t)b * N_ + r0 + rg + 12) * DIM_ + h * DH_ + d] = f2bf(o3 * dinv[rg + 12]);
}

// ---------------- final: out = x + attn @ Wo^T + bo (store per flag) ----------------
__global__ __launch_bounds__(256) void final_gemm(
    const unsigned short* __restrict__ attn, const unsigned short* __restrict__ Wo,
    const unsigned short* __restrict__ bo, const unsigned short* __restrict__ x,
    void* __restrict__ outv, const int* __restrict__ flag) {
  __shared__ float As[16][68];
  __shared__ float Bs[16][68];
  const int tid = threadIdx.x;
  const int tx = tid & 15, ty = tid >> 4;
  const int tm0 = blockIdx.x * 64, tn0 = blockIdx.y * 64;
  const int lr = tid >> 2, lc = (tid & 3) << 2;
  const int f = *flag;
  float acc[4][4] = {};
  for (int k0 = 0; k0 < DIM_; k0 += 16) {
    const ushort4 ua = *(const ushort4*)&attn[(size_t)(tm0 + lr) * DIM_ + k0 + lc];
    const ushort4 ub = *(const ushort4*)&Wo[(size_t)(tn0 + lr) * DIM_ + k0 + lc];
    As[lc + 0][lr] = bfu(ua.x); As[lc + 1][lr] = bfu(ua.y);
    As[lc + 2][lr] = bfu(ua.z); As[lc + 3][lr] = bfu(ua.w);
    Bs[lc + 0][lr] = bfu(ub.x); Bs[lc + 1][lr] = bfu(ub.y);
    Bs[lc + 2][lr] = bfu(ub.z); Bs[lc + 3][lr] = bfu(ub.w);
    __syncthreads();
#pragma unroll
    for (int kk = 0; kk < 16; ++kk) {
      const float4 av = *(const float4*)&As[kk][ty * 4];
      const float4 bv = *(const float4*)&Bs[kk][tx * 4];
      acc[0][0] += av.x * bv.x; acc[0][1] += av.x * bv.y; acc[0][2] += av.x * bv.z; acc[0][3] += av.x * bv.w;
      acc[1][0] += av.y * bv.x; acc[1][1] += av.y * bv.y; acc[1][2] += av.y * bv.z; acc[1][3] += av.y * bv.w;
      acc[2][0] += av.z * bv.x; acc[2][1] += av.z * bv.y; acc[2][2] += av.z * bv.z; acc[2][3] += av.z * bv.w;
      acc[3][0] += av.w * bv.x; acc[3][1] += av.w * bv.y; acc[3][2] += av.w * bv.z; acc[3][3] += av.w * bv.w;
    }
    __syncthreads();
  }
#pragma unroll
  for (int i = 0; i < 4; ++i) {
    const int t = tm0 + ty * 4 + i;
#pragma unroll
    for (int j = 0; j < 4; ++j) {
      const int c = tn0 + tx * 4 + j;
      const float rv = acc[i][j] + bfu(bo[c]) + bfu(x[(size_t)t * DIM_ + c]);
      const size_t idx = (size_t)t * DIM_ + c;
      if (f) ((float*)outv)[idx] = rv;
      else   ((unsigned short*)outv)[idx] = f2bf(rv);
    }
  }
}

extern "C" void kernel_launch(void* const* d_in, const int* in_sizes, int n_in,
                              void* d_out, int out_size, void* d_ws, size_t ws_size,
                              hipStream_t stream) {
  int* flag = (int*)d_ws;
  float* wsf = (float*)d_ws;
  float* ctx = wsf + CTXF;
  float* ksum = wsf + KSUMF;
  float* part = wsf + PARTF;
  float* kmax = wsf + KMAXF;
  unsigned short* canon = (unsigned short*)((char*)d_ws + CANON_BYTE);
  unsigned short* cx = canon;
  unsigned short* cWq = cx + XN;
  unsigned short* cWk = cWq + WN;
  unsigned short* cWv = cWk + WN;
  unsigned short* cWo = cWv + WN;
  unsigned short* cbo = cWo + WN;
  unsigned short* cpj = cbo + BON;
  unsigned short* qkv = cpj + PJN;
  unsigned short* Q = qkv;
  unsigned short* K = qkv + XN;
  unsigned short* V = qkv + 2 * XN;
  unsigned short* attn = K;  // K dead after ctx_kernel

  detect_kernel<<<1, 256, 0, stream>>>((const unsigned short*)d_in[0], flag);
  canon_kernel<<<512, 256, 0, stream>>>(d_in[0], cx, (int)XN, flag);
  canon_kernel<<<128, 256, 0, stream>>>(d_in[1], cWq, (int)WN, flag);
  canon_kernel<<<128, 256, 0, stream>>>(d_in[2], cWk, (int)WN, flag);
  canon_kernel<<<128, 256, 0, stream>>>(d_in[3], cWv, (int)WN, flag);
  canon_kernel<<<128, 256, 0, stream>>>(d_in[4], cWo, (int)WN, flag);
  canon_kernel<<<2, 256, 0, stream>>>(d_in[5], cbo, (int)BON, flag);
  canon_kernel<<<17, 256, 0, stream>>>(d_in[6], cpj, (int)PJN, flag);

  qkv_gemm<<<dim3(NT_ / 64, DIM_ / 64, 3), 256, 0, stream>>>(cx, cWq, cWk, cWv, qkv);
  kmax_part_kernel<<<dim3(BH_, 16), 256, 0, stream>>>(K, cpj, part);
  zero_kernel<<<dim3(1024), 256, 0, stream>>>(ctx, 544768 + 8512);
  kmax_reduce<<<1, 64, 0, stream>>>(part, kmax);
  ctx_kernel<<<dim3(BH_, 8), 256, 0, stream>>>(K, V, cpj, kmax, ctx, ksum);
  out_kernel<<<dim3(BH_, N_ / 16), 256, 0, stream>>>(Q, cpj, ctx, ksum, attn);
  final_gemm<<<dim3(NT_ / 64, DIM_ / 64), 256, 0, stream>>>(attn, cWo, cbo, cx, d_out, flag);
}

// Round 7
// 673.893 us; speedup vs baseline: 4.0895x; 4.0895x over previous
//
#include <hip/hip_runtime.h>

#define N_ 4096
#define DIM_ 512
#define H_ 8
#define DH_ 64
#define M_ 266
#define MP_ 272      // 17 tiles of 16
#define MP2_ 288     // out-GEMM K padded to 9 chunks of 32
#define NT_ 16384
#define BH_ 32

#define NORMC 0.3535533905932738f   // 64^-0.25
#define RATIOC 0.06131393394849658f // 266^-0.5
#define EPSK 1e-4f
#define DIAGC 0.0625f               // 0.5 * normalizer^2

// ---- ws layout (byte offsets), total 70,979,712 B < proven 71,456,400 ----
#define PROJP_B 0ul                        // 272*64*2 = 34816
#define KMAX_B  34816ul                    // 32*4 = 128
#define KSUM_B  34944ul                    // 32*272*4 = 34816
#define DIAGQ_B 69760ul                    // 131072*2 (bf16) = 262144
#define DIAGK_B 331904ul                   // 262144
#define CTXT_B  594048ul                   // 32*64*288*2 = 1179648
#define XBF_B   1773696ul                  // 8388608*2 = 16777216
#define WQ_B    18550912ul                 // 262144*2 = 524288
#define WK_B    19075200ul
#define WV_B    19599488ul
#define WO_B    20123776ul
#define Q_B     20648064ul                 // 16777216
#define K_B     37425280ul                 // 16777216 (attn aliases this)
#define VT_B    54202496ul                 // 16777216 -> ends 70979712

typedef __bf16 bf16x8 __attribute__((ext_vector_type(8)));
typedef float f32x4 __attribute__((ext_vector_type(4)));
#define MFMA16(a, b, c) __builtin_amdgcn_mfma_f32_16x16x32_bf16((a), (b), (c), 0, 0, 0)

__device__ __forceinline__ float bfu(unsigned short u) {
  union { unsigned int i; float f; } x; x.i = ((unsigned int)u) << 16; return x.f;
}
__device__ __forceinline__ unsigned short f2bf(float f) {
  union { float f; unsigned int i; } u; u.f = f;
  unsigned int r = u.i + 0x7fffu + ((u.i >> 16) & 1u);
  return (unsigned short)(r >> 16);
}
__device__ __forceinline__ void atomicMaxF(float* addr, float val) {
  int* ai = (int*)addr;
  while (true) {
    float cur = __int_as_float(*(volatile int*)ai);
    if (val <= cur) break;
    int old = atomicCAS(ai, __float_as_int(cur), __float_as_int(val));
    if (old == __float_as_int(cur)) break;
  }
}

// ---------------- fp32 -> bf16 conversion (n multiple of 4) ----------------
__global__ void cvt_kernel(const float* __restrict__ src, unsigned short* __restrict__ dst, int n) {
  int i = (blockIdx.x * 256 + threadIdx.x) * 4;
  const int stride = gridDim.x * 1024;
  for (; i < n; i += stride) {
    const float4 v = *(const float4*)(src + i);
    ushort4 u;
    u.x = f2bf(v.x); u.y = f2bf(v.y); u.z = f2bf(v.z); u.w = f2bf(v.w);
    *(ushort4*)(dst + i) = u;
  }
}

// ---------------- setup: proj cvt+pad, kmax init, ctxT zero ----------------
__global__ void setup_kernel(const float* __restrict__ proj,
                             unsigned short* __restrict__ projp,
                             float* __restrict__ kmax,
                             unsigned short* __restrict__ ctxT) {
  const int i = blockIdx.x * 256 + threadIdx.x;
  const int stride = gridDim.x * 256;
  for (int j = i; j < MP_ * DH_; j += stride)
    projp[j] = (j < M_ * DH_) ? f2bf(proj[j]) : (unsigned short)0;
  for (int j = i; j < BH_; j += stride) kmax[j] = -3e38f;
  for (int j = i; j < BH_ * DH_ * MP2_; j += stride) ctxT[j] = 0;
}

// ---------------- QKV projection (MFMA): Q,K (t,e); V transposed ----------------
__global__ __launch_bounds__(256) void qkv_mfma(
    const unsigned short* __restrict__ x, const unsigned short* __restrict__ Wq,
    const unsigned short* __restrict__ Wk, const unsigned short* __restrict__ Wv,
    unsigned short* __restrict__ Q, unsigned short* __restrict__ K,
    unsigned short* __restrict__ VT) {
  const int z = blockIdx.z;
  const unsigned short* W = (z == 0) ? Wq : (z == 1) ? Wk : Wv;
  const int t0 = blockIdx.x * 64, e0 = blockIdx.y * 64;
  const int wv = threadIdx.x >> 6, lane = threadIdx.x & 63;
  const int r = lane & 15, q = lane >> 4;
  f32x4 acc[4];
#pragma unroll
  for (int i = 0; i < 4; ++i) acc[i] = (f32x4){0.f, 0.f, 0.f, 0.f};
  const unsigned short* arow = x + (size_t)(t0 + wv * 16 + r) * DIM_;
#pragma unroll 4
  for (int kc = 0; kc < 16; ++kc) {
    const int ko = kc * 32 + q * 8;
    const bf16x8 a = *(const bf16x8*)(arow + ko);
#pragma unroll
    for (int ct = 0; ct < 4; ++ct) {
      const bf16x8 b = *(const bf16x8*)(W + (size_t)(e0 + ct * 16 + r) * DIM_ + ko);
      acc[ct] = MFMA16(a, b, acc[ct]);
    }
  }
  if (z < 2) {
    unsigned short* dst = (z == 0) ? Q : K;
#pragma unroll
    for (int ct = 0; ct < 4; ++ct) {
      const int e = e0 + ct * 16 + r;
#pragma unroll
      for (int i = 0; i < 4; ++i) {
        const int t = t0 + wv * 16 + q * 4 + i;
        dst[(size_t)t * DIM_ + e] = f2bf(acc[ct][i]);
      }
    }
  } else {
#pragma unroll
    for (int ct = 0; ct < 4; ++ct) {
      const int e = e0 + ct * 16 + r;
      const int h = e >> 6, dh = e & 63;
      const int t = t0 + wv * 16 + q * 4;
      const int b_ = t >> 12, n = t & (N_ - 1);
      ushort4 pk;
      pk.x = f2bf(acc[ct][0]); pk.y = f2bf(acc[ct][1]);
      pk.z = f2bf(acc[ct][2]); pk.w = f2bf(acc[ct][3]);
      *(ushort4*)&VT[((size_t)((b_ * H_ + h) * DH_ + dh)) * N_ + n] = pk;
    }
  }
}

// ---------------- diag: DIAGC * sum(t*t) per (bh, n), stored bf16 ----------------
__global__ void diag_kernel(const unsigned short* __restrict__ Q,
                            const unsigned short* __restrict__ K,
                            unsigned short* __restrict__ dq, unsigned short* __restrict__ dk) {
  const int i = blockIdx.x * 256 + threadIdx.x;  // bh*4096 + n
  const int bh = i >> 12, n = i & (N_ - 1);
  const int b_ = bh >> 3, h = bh & 7;
  const unsigned short* src = ((blockIdx.y == 0) ? Q : K) + (size_t)(b_ * N_ + n) * DIM_ + h * DH_;
  float s = 0.f;
#pragma unroll
  for (int c = 0; c < 16; ++c) {
    const ushort4 u = ((const ushort4*)src)[c];
    const float a = bfu(u.x), b2 = bfu(u.y), cc = bfu(u.z), d = bfu(u.w);
    s += a * a + b2 * b2 + cc * cc + d * d;
  }
  ((blockIdx.y == 0) ? dq : dk)[i] = f2bf(s * DIAGC);
}

// ---------------- kmax (MFMA): per-bh max over (n, m<266) of NORMC*(K.projT) ----------------
__global__ __launch_bounds__(256) void kmax_mfma(
    const unsigned short* __restrict__ K, const unsigned short* __restrict__ projp,
    float* __restrict__ kmax) {
  const int bh = blockIdx.x, n0 = blockIdx.y * 64;
  const int wv = threadIdx.x >> 6, lane = threadIdx.x & 63;
  const int r = lane & 15, q = lane >> 4;
  const int b_ = bh >> 3, h = bh & 7;
  const int n = n0 + wv * 16 + r;
  const unsigned short* krow = K + (size_t)(b_ * N_ + n) * DIM_ + h * DH_;
  const bf16x8 kb0 = *(const bf16x8*)(krow + q * 8);
  const bf16x8 kb1 = *(const bf16x8*)(krow + 32 + q * 8);
  float runmax = -3e38f;
  for (int mt = 0; mt < 17; ++mt) {
    const unsigned short* prow = projp + (size_t)(mt * 16 + r) * DH_;
    const bf16x8 a0 = *(const bf16x8*)(prow + q * 8);
    const bf16x8 a1 = *(const bf16x8*)(prow + 32 + q * 8);
    f32x4 acc = (f32x4){0.f, 0.f, 0.f, 0.f};
    acc = MFMA16(a0, kb0, acc);
    acc = MFMA16(a1, kb1, acc);
#pragma unroll
    for (int i = 0; i < 4; ++i) {
      const int m = mt * 16 + q * 4 + i;
      if (m < M_) runmax = fmaxf(runmax, acc[i]);
    }
  }
  for (int s2 = 1; s2 < 64; s2 <<= 1) runmax = fmaxf(runmax, __shfl_xor(runmax, s2, 64));
  __shared__ float wm[4];
  if (lane == 0) wm[wv] = runmax;
  __syncthreads();
  if (threadIdx.x == 0) {
    const float m = fmaxf(fmaxf(wm[0], wm[1]), fmaxf(wm[2], wm[3])) * NORMC;
    atomicMaxF(&kmax[bh], m);
  }
}

// ---------------- fused: td -> exp -> kp; ctx += kp x VT; ksum ----------------
__global__ __launch_bounds__(256) void ctxfused_mfma(
    const unsigned short* __restrict__ K, const unsigned short* __restrict__ VT,
    const unsigned short* __restrict__ projp, const unsigned short* __restrict__ diag_k,
    const float* __restrict__ kmaxv, float* __restrict__ ksum,
    unsigned short* __restrict__ ctxT) {
  __shared__ unsigned short kll[64][72];
  __shared__ unsigned short vtl[64][72];
  __shared__ unsigned short kpl[16][72];
  __shared__ float wks[4][16];
  const int bh = blockIdx.x, mt = blockIdx.y;
  const int wv = threadIdx.x >> 6, lane = threadIdx.x & 63;
  const int r = lane & 15, q = lane >> 4;
  const int b_ = bh >> 3, h = bh & 7;
  const int m0 = mt * 16;
  const float km = kmaxv[bh];
  const unsigned short* prow = projp + (size_t)(m0 + r) * DH_;
  const bf16x8 p0 = *(const bf16x8*)(prow + q * 8);
  const bf16x8 p1 = *(const bf16x8*)(prow + 32 + q * 8);
  const unsigned short* kbase = K + (size_t)(b_ * N_) * DIM_ + h * DH_;
  const unsigned short* vbase = VT + (size_t)bh * DH_ * N_;
  f32x4 cacc = (f32x4){0.f, 0.f, 0.f, 0.f};
  float ksa[4] = {0.f, 0.f, 0.f, 0.f};
  for (int nc = 0; nc < 64; ++nc) {
    const int n0c = nc * 64;
#pragma unroll
    for (int j = 0; j < 4; ++j) {
      const int idx = threadIdx.x + j * 256;
      const int rr = idx >> 4, c4 = (idx & 15) << 2;
      *(ushort4*)&kll[rr][c4] = *(const ushort4*)&kbase[(size_t)(n0c + rr) * DIM_ + c4];
      *(ushort4*)&vtl[rr][c4] = *(const ushort4*)&vbase[(size_t)rr * N_ + n0c + c4];
    }
    __syncthreads();
    {
      const bf16x8 kb0 = *(const bf16x8*)&kll[wv * 16 + r][q * 8];
      const bf16x8 kb1 = *(const bf16x8*)&kll[wv * 16 + r][32 + q * 8];
      f32x4 acc = (f32x4){0.f, 0.f, 0.f, 0.f};
      acc = MFMA16(p0, kb0, acc);
      acc = MFMA16(p1, kb1, acc);
      const float dgk = bfu(diag_k[bh * N_ + n0c + wv * 16 + r]);
#pragma unroll
      for (int i = 0; i < 4; ++i) {
        const int m = m0 + q * 4 + i;
        float kp = 0.f;
        if (m < M_) {
          const float arg = fminf(NORMC * acc[i] - dgk - km, 0.f);
          kp = RATIOC * (__expf(arg) + EPSK);
        }
        kpl[q * 4 + i][wv * 16 + r] = f2bf(kp);
        ksa[i] += kp;
      }
    }
    __syncthreads();
    {
      const bf16x8 a0 = *(const bf16x8*)&kpl[r][q * 8];
      const bf16x8 a1 = *(const bf16x8*)&kpl[r][32 + q * 8];
      const bf16x8 b0 = *(const bf16x8*)&vtl[wv * 16 + r][q * 8];
      const bf16x8 b1 = *(const bf16x8*)&vtl[wv * 16 + r][32 + q * 8];
      cacc = MFMA16(a0, b0, cacc);
      cacc = MFMA16(a1, b1, cacc);
    }
    __syncthreads();
  }
  {
    const int d = wv * 16 + r;
    ushort4 pk;
    pk.x = f2bf(cacc[0]); pk.y = f2bf(cacc[1]);
    pk.z = f2bf(cacc[2]); pk.w = f2bf(cacc[3]);
    *(ushort4*)&ctxT[((size_t)bh * DH_ + d) * MP2_ + m0 + q * 4] = pk;
  }
#pragma unroll
  for (int i = 0; i < 4; ++i)
    for (int s2 = 1; s2 < 16; s2 <<= 1) ksa[i] += __shfl_xor(ksa[i], s2, 64);
  if (r == 0) {
#pragma unroll
    for (int i = 0; i < 4; ++i) wks[wv][q * 4 + i] = ksa[i];
  }
  __syncthreads();
  if (threadIdx.x < 16)
    ksum[bh * MP_ + m0 + threadIdx.x] =
        wks[0][threadIdx.x] + wks[1][threadIdx.x] + wks[2][threadIdx.x] + wks[3][threadIdx.x];
}

// ---------------- fused QP + out GEMM ----------------
__global__ __launch_bounds__(256) void qpout_mfma(
    const unsigned short* __restrict__ Qb, const unsigned short* __restrict__ projp,
    const unsigned short* __restrict__ diag_q, const float* __restrict__ ksum,
    const unsigned short* __restrict__ ctxT, unsigned short* __restrict__ attn) {
  __shared__ unsigned short qps[64][296];
  __shared__ float ksums[MP_];
  __shared__ float dinvs[64];
  __shared__ float parts[4][64];
  const int bh = blockIdx.x, n0 = blockIdx.y * 64;
  const int wv = threadIdx.x >> 6, lane = threadIdx.x & 63;
  const int r = lane & 15, q = lane >> 4;
  const int b_ = bh >> 3, h = bh & 7;
  for (int i = threadIdx.x; i < MP_; i += 256) ksums[i] = ksum[bh * MP_ + i];
  for (int i = threadIdx.x; i < 64 * 24; i += 256) qps[i / 24][MP_ + (i % 24)] = 0;
  const int nrow = n0 + wv * 16 + r;
  const unsigned short* qrow = Qb + (size_t)(b_ * N_ + nrow) * DIM_ + h * DH_;
  const bf16x8 a0 = *(const bf16x8*)(qrow + q * 8);
  const bf16x8 a1 = *(const bf16x8*)(qrow + 32 + q * 8);
  float tdv[17][4];
  for (int mt = 0; mt < 17; ++mt) {
    const unsigned short* prow = projp + (size_t)(mt * 16 + r) * DH_;
    const bf16x8 p0 = *(const bf16x8*)(prow + q * 8);
    const bf16x8 p1 = *(const bf16x8*)(prow + 32 + q * 8);
    f32x4 acc = (f32x4){0.f, 0.f, 0.f, 0.f};
    acc = MFMA16(a0, p0, acc);
    acc = MFMA16(a1, p1, acc);
#pragma unroll
    for (int i = 0; i < 4; ++i) tdv[mt][i] = NORMC * acc[i];
  }
  float rmax[4];
#pragma unroll
  for (int i = 0; i < 4; ++i) {
    float v = -3e38f;
    for (int mt = 0; mt < 17; ++mt) {
      const int m = mt * 16 + r;
      if (m < M_) v = fmaxf(v, tdv[mt][i]);
    }
    rmax[i] = v;
  }
  for (int s2 = 1; s2 < 16; s2 <<= 1)
#pragma unroll
    for (int i = 0; i < 4; ++i) rmax[i] = fmaxf(rmax[i], __shfl_xor(rmax[i], s2, 64));
  float dgq[4];
#pragma unroll
  for (int i = 0; i < 4; ++i) dgq[i] = bfu(diag_q[bh * N_ + n0 + wv * 16 + q * 4 + i]);
  for (int mt = 0; mt < 17; ++mt) {
#pragma unroll
    for (int i = 0; i < 4; ++i) {
      const int m = mt * 16 + r;
      float qp = 0.f;
      if (m < M_) {
        const float arg = fminf(tdv[mt][i] - dgq[i] - rmax[i], 0.f);
        qp = RATIOC * (__expf(arg) + EPSK);
      }
      qps[wv * 16 + q * 4 + i][m] = f2bf(qp);
    }
  }
  __syncthreads();
  {
    const int row = threadIdx.x & 63, seg = threadIdx.x >> 6;
    const int ms = seg * 68, me = (ms + 68 < MP_) ? ms + 68 : MP_;
    float s = 0.f;
    for (int m = ms; m < me; ++m) s += bfu(qps[row][m]) * ksums[m];
    parts[seg][row] = s;
  }
  __syncthreads();
  if (threadIdx.x < 64) {
    const float s = parts[0][threadIdx.x] + parts[1][threadIdx.x] +
                    parts[2][threadIdx.x] + parts[3][threadIdx.x];
    dinvs[threadIdx.x] = 1.f / fmaxf(s, 1e-30f);
  }
  __syncthreads();
  f32x4 oacc[4];
#pragma unroll
  for (int i = 0; i < 4; ++i) oacc[i] = (f32x4){0.f, 0.f, 0.f, 0.f};
  const unsigned short* cbase = ctxT + (size_t)bh * DH_ * MP2_;
  for (int kc = 0; kc < 9; ++kc) {
    const bf16x8 a = *(const bf16x8*)&qps[wv * 16 + r][kc * 32 + q * 8];
#pragma unroll
    for (int dt = 0; dt < 4; ++dt) {
      const bf16x8 b = *(const bf16x8*)&cbase[(size_t)(dt * 16 + r) * MP2_ + kc * 32 + q * 8];
      oacc[dt] = MFMA16(a, b, oacc[dt]);
    }
  }
#pragma unroll
  for (int dt = 0; dt < 4; ++dt) {
    const int d = dt * 16 + r;
#pragma unroll
    for (int i = 0; i < 4; ++i) {
      const int nn = wv * 16 + q * 4 + i;
      const float o = oacc[dt][i] * dinvs[nn];
      attn[(size_t)(b_ * N_ + n0 + nn) * DIM_ + h * DH_ + d] = f2bf(o);
    }
  }
}

// ---------------- final (MFMA): out = x + attn @ Wo^T + bo (fp32 I/O) ----------------
__global__ __launch_bounds__(256) void final_mfma(
    const unsigned short* __restrict__ attn, const unsigned short* __restrict__ Wo,
    const float* __restrict__ bo, const float* __restrict__ x,
    float* __restrict__ out) {
  const int t0 = blockIdx.x * 64, e0 = blockIdx.y * 64;
  const int wv = threadIdx.x >> 6, lane = threadIdx.x & 63;
  const int r = lane & 15, q = lane >> 4;
  f32x4 acc[4];
#pragma unroll
  for (int i = 0; i < 4; ++i) acc[i] = (f32x4){0.f, 0.f, 0.f, 0.f};
  const unsigned short* arow = attn + (size_t)(t0 + wv * 16 + r) * DIM_;
#pragma unroll 4
  for (int kc = 0; kc < 16; ++kc) {
    const int ko = kc * 32 + q * 8;
    const bf16x8 a = *(const bf16x8*)(arow + ko);
#pragma unroll
    for (int ct = 0; ct < 4; ++ct) {
      const bf16x8 b = *(const bf16x8*)(Wo + (size_t)(e0 + ct * 16 + r) * DIM_ + ko);
      acc[ct] = MFMA16(a, b, acc[ct]);
    }
  }
#pragma unroll
  for (int ct = 0; ct < 4; ++ct) {
    const int c = e0 + ct * 16 + r;
    const float bov = bo[c];
#pragma unroll
    for (int i = 0; i < 4; ++i) {
      const int t = t0 + wv * 16 + q * 4 + i;
      out[(size_t)t * DIM_ + c] = acc[ct][i] + bov + x[(size_t)t * DIM_ + c];
    }
  }
}

extern "C" void kernel_launch(void* const* d_in, const int* in_sizes, int n_in,
                              void* d_out, int out_size, void* d_ws, size_t ws_size,
                              hipStream_t stream) {
  const float* x = (const float*)d_in[0];
  const float* Wq = (const float*)d_in[1];
  const float* Wk = (const float*)d_in[2];
  const float* Wv = (const float*)d_in[3];
  const float* Wo = (const float*)d_in[4];
  const float* bo = (const float*)d_in[5];
  const float* proj = (const float*)d_in[6];
  char* ws = (char*)d_ws;
  unsigned short* projp = (unsigned short*)(ws + PROJP_B);
  float* kmax = (float*)(ws + KMAX_B);
  float* ksum = (float*)(ws + KSUM_B);
  unsigned short* diag_q = (unsigned short*)(ws + DIAGQ_B);
  unsigned short* diag_k = (unsigned short*)(ws + DIAGK_B);
  unsigned short* ctxT = (unsigned short*)(ws + CTXT_B);
  unsigned short* xbf = (unsigned short*)(ws + XBF_B);
  unsigned short* wqb = (unsigned short*)(ws + WQ_B);
  unsigned short* wkb = (unsigned short*)(ws + WK_B);
  unsigned short* wvb = (unsigned short*)(ws + WV_B);
  unsigned short* wob = (unsigned short*)(ws + WO_B);
  unsigned short* Q = (unsigned short*)(ws + Q_B);
  unsigned short* K = (unsigned short*)(ws + K_B);
  unsigned short* VT = (unsigned short*)(ws + VT_B);
  unsigned short* attn = K;  // K dead after ctxfused_mfma
  float* out = (float*)d_out;

  cvt_kernel<<<1024, 256, 0, stream>>>(x, xbf, 8388608);
  cvt_kernel<<<128, 256, 0, stream>>>(Wq, wqb, 262144);
  cvt_kernel<<<128, 256, 0, stream>>>(Wk, wkb, 262144);
  cvt_kernel<<<128, 256, 0, stream>>>(Wv, wvb, 262144);
  cvt_kernel<<<128, 256, 0, stream>>>(Wo, wob, 262144);
  setup_kernel<<<512, 256, 0, stream>>>(proj, projp, kmax, ctxT);
  qkv_mfma<<<dim3(NT_ / 64, DIM_ / 64, 3), 256, 0, stream>>>(xbf, wqb, wkb, wvb, Q, K, VT);
  diag_kernel<<<dim3(512, 2), 256, 0, stream>>>(Q, K, diag_q, diag_k);
  kmax_mfma<<<dim3(BH_, 64), 256, 0, stream>>>(K, projp, kmax);
  ctxfused_mfma<<<dim3(BH_, 17), 256, 0, stream>>>(K, VT, projp, diag_k, kmax, ksum, ctxT);
  qpout_mfma<<<dim3(BH_, 64), 256, 0, stream>>>(Q, projp, diag_q, ksum, ctxT, attn);
  final_mfma<<<dim3(NT_ / 64, DIM_ / 64), 256, 0, stream>>>(attn, wob, bo, x, out);
}

// Round 8
// 457.161 us; speedup vs baseline: 6.0282x; 1.4741x over previous
//
#include <hip/hip_runtime.h>

#define N_ 4096
#define DIM_ 512
#define H_ 8
#define DH_ 64
#define M_ 266
#define MP_ 272      // 17 tiles of 16
#define MP2_ 288     // out-GEMM K padded to 9 chunks of 32
#define NT_ 16384
#define BH_ 32

#define NORMC 0.3535533905932738f   // 64^-0.25
#define RATIOC 0.06131393394849658f // 266^-0.5
#define EPSK 1e-4f
#define DIAGC 0.0625f               // 0.5 * normalizer^2

// ---- ws layout (byte offsets), total 70,979,712 B ----
#define PROJP_B 0ul
#define KMAX_B  34816ul
#define KSUM_B  34944ul
#define DIAGQ_B 69760ul
#define DIAGK_B 331904ul
#define CTXT_B  594048ul
#define XBF_B   1773696ul
#define WQ_B    18550912ul
#define WK_B    19075200ul
#define WV_B    19599488ul
#define WO_B    20123776ul
#define Q_B     20648064ul
#define K_B     37425280ul
#define VT_B    54202496ul

typedef __bf16 bf16x8 __attribute__((ext_vector_type(8)));
typedef float f32x4 __attribute__((ext_vector_type(4)));
#define MFMA16(a, b, c) __builtin_amdgcn_mfma_f32_16x16x32_bf16((a), (b), (c), 0, 0, 0)

__device__ __forceinline__ float bfu(unsigned short u) {
  union { unsigned int i; float f; } x; x.i = ((unsigned int)u) << 16; return x.f;
}
__device__ __forceinline__ unsigned short f2bf(float f) {
  union { float f; unsigned int i; } u; u.f = f;
  unsigned int r = u.i + 0x7fffu + ((u.i >> 16) & 1u);
  return (unsigned short)(r >> 16);
}
__device__ __forceinline__ void atomicMaxF(float* addr, float val) {
  int* ai = (int*)addr;
  while (true) {
    float cur = __int_as_float(*(volatile int*)ai);
    if (val <= cur) break;
    int old = atomicCAS(ai, __float_as_int(cur), __float_as_int(val));
    if (old == __float_as_int(cur)) break;
  }
}

// ---------------- fp32 -> bf16 conversion ----------------
__global__ void cvt_kernel(const float* __restrict__ src, unsigned short* __restrict__ dst, int n) {
  int i = (blockIdx.x * 256 + threadIdx.x) * 4;
  const int stride = gridDim.x * 1024;
  for (; i < n; i += stride) {
    const float4 v = *(const float4*)(src + i);
    ushort4 u;
    u.x = f2bf(v.x); u.y = f2bf(v.y); u.z = f2bf(v.z); u.w = f2bf(v.w);
    *(ushort4*)(dst + i) = u;
  }
}

// ---------------- setup: proj cvt+pad, kmax init, ctxT zero ----------------
__global__ void setup_kernel(const float* __restrict__ proj,
                             unsigned short* __restrict__ projp,
                             float* __restrict__ kmax,
                             unsigned short* __restrict__ ctxT) {
  const int i = blockIdx.x * 256 + threadIdx.x;
  const int stride = gridDim.x * 256;
  for (int j = i; j < MP_ * DH_; j += stride)
    projp[j] = (j < M_ * DH_) ? f2bf(proj[j]) : (unsigned short)0;
  for (int j = i; j < BH_; j += stride) kmax[j] = -3e38f;
  for (int j = i; j < BH_ * DH_ * MP2_; j += stride) ctxT[j] = 0;
}

// ---------------- QKV projection: 128x128 LDS-staged MFMA GEMM ----------------
__global__ __launch_bounds__(256) void qkv_mfma(
    const unsigned short* __restrict__ x, const unsigned short* __restrict__ Wq,
    const unsigned short* __restrict__ Wk, const unsigned short* __restrict__ Wv,
    unsigned short* __restrict__ Q, unsigned short* __restrict__ K,
    unsigned short* __restrict__ VT) {
  __shared__ unsigned short As[128 * 64];
  __shared__ unsigned short Bs[128 * 64];
  const int z = blockIdx.z;
  const unsigned short* W = (z == 0) ? Wq : (z == 1) ? Wk : Wv;
  const int t0 = blockIdx.x * 128, e0 = blockIdx.y * 128;
  const int tid = threadIdx.x;
  const int wv = tid >> 6, lane = tid & 63;
  const int r = lane & 15, q = lane >> 4;
  const int wr = (wv >> 1) * 64, wc = (wv & 1) * 64;
  f32x4 acc[4][4];
#pragma unroll
  for (int i = 0; i < 4; ++i)
#pragma unroll
    for (int j = 0; j < 4; ++j) acc[i][j] = (f32x4){0.f, 0.f, 0.f, 0.f};
  const int srow = tid >> 3, scol = (tid & 7) * 8;
  for (int k0 = 0; k0 < DIM_; k0 += 64) {
#pragma unroll
    for (int j = 0; j < 4; ++j) {
      const int rr = srow + j * 32;
      *(uint4*)&As[rr * 64 + scol] = *(const uint4*)&x[(size_t)(t0 + rr) * DIM_ + k0 + scol];
      *(uint4*)&Bs[rr * 64 + scol] = *(const uint4*)&W[(size_t)(e0 + rr) * DIM_ + k0 + scol];
    }
    __syncthreads();
#pragma unroll
    for (int kc = 0; kc < 2; ++kc) {
      bf16x8 af[4], bfr[4];
#pragma unroll
      for (int rt = 0; rt < 4; ++rt)
        af[rt] = *(const bf16x8*)&As[(wr + rt * 16 + r) * 64 + kc * 32 + q * 8];
#pragma unroll
      for (int ct = 0; ct < 4; ++ct)
        bfr[ct] = *(const bf16x8*)&Bs[(wc + ct * 16 + r) * 64 + kc * 32 + q * 8];
#pragma unroll
      for (int rt = 0; rt < 4; ++rt)
#pragma unroll
        for (int ct = 0; ct < 4; ++ct)
          acc[rt][ct] = MFMA16(af[rt], bfr[ct], acc[rt][ct]);
    }
    __syncthreads();
  }
  if (z < 2) {
    unsigned short* dst = (z == 0) ? Q : K;
#pragma unroll
    for (int rt = 0; rt < 4; ++rt) {
#pragma unroll
      for (int ct = 0; ct < 4; ++ct) {
        const int e = e0 + wc + ct * 16 + r;
#pragma unroll
        for (int i = 0; i < 4; ++i) {
          const int t = t0 + wr + rt * 16 + q * 4 + i;
          dst[(size_t)t * DIM_ + e] = f2bf(acc[rt][ct][i]);
        }
      }
    }
  } else {
#pragma unroll
    for (int rt = 0; rt < 4; ++rt) {
      const int t = t0 + wr + rt * 16 + q * 4;
      const int b_ = t >> 12, n = t & (N_ - 1);
#pragma unroll
      for (int ct = 0; ct < 4; ++ct) {
        const int e = e0 + wc + ct * 16 + r;
        const int h = e >> 6, dh = e & 63;
        ushort4 pk;
        pk.x = f2bf(acc[rt][ct][0]); pk.y = f2bf(acc[rt][ct][1]);
        pk.z = f2bf(acc[rt][ct][2]); pk.w = f2bf(acc[rt][ct][3]);
        *(ushort4*)&VT[((size_t)((b_ * H_ + h) * DH_ + dh)) * N_ + n] = pk;
      }
    }
  }
}

// ---------------- diag: DIAGC * sum(t*t) per (bh, n), stored bf16 ----------------
__global__ void diag_kernel(const unsigned short* __restrict__ Q,
                            const unsigned short* __restrict__ K,
                            unsigned short* __restrict__ dq, unsigned short* __restrict__ dk) {
  const int i = blockIdx.x * 256 + threadIdx.x;
  const int bh = i >> 12, n = i & (N_ - 1);
  const int b_ = bh >> 3, h = bh & 7;
  const unsigned short* src = ((blockIdx.y == 0) ? Q : K) + (size_t)(b_ * N_ + n) * DIM_ + h * DH_;
  float s = 0.f;
#pragma unroll
  for (int c = 0; c < 16; ++c) {
    const ushort4 u = ((const ushort4*)src)[c];
    const float a = bfu(u.x), b2 = bfu(u.y), cc = bfu(u.z), d = bfu(u.w);
    s += a * a + b2 * b2 + cc * cc + d * d;
  }
  ((blockIdx.y == 0) ? dq : dk)[i] = f2bf(s * DIAGC);
}

// ---------------- kmax (MFMA) ----------------
__global__ __launch_bounds__(256) void kmax_mfma(
    const unsigned short* __restrict__ K, const unsigned short* __restrict__ projp,
    float* __restrict__ kmax) {
  const int bh = blockIdx.x, n0 = blockIdx.y * 64;
  const int wv = threadIdx.x >> 6, lane = threadIdx.x & 63;
  const int r = lane & 15, q = lane >> 4;
  const int b_ = bh >> 3, h = bh & 7;
  const int n = n0 + wv * 16 + r;
  const unsigned short* krow = K + (size_t)(b_ * N_ + n) * DIM_ + h * DH_;
  const bf16x8 kb0 = *(const bf16x8*)(krow + q * 8);
  const bf16x8 kb1 = *(const bf16x8*)(krow + 32 + q * 8);
  float runmax = -3e38f;
  for (int mt = 0; mt < 17; ++mt) {
    const unsigned short* prow = projp + (size_t)(mt * 16 + r) * DH_;
    const bf16x8 a0 = *(const bf16x8*)(prow + q * 8);
    const bf16x8 a1 = *(const bf16x8*)(prow + 32 + q * 8);
    f32x4 acc = (f32x4){0.f, 0.f, 0.f, 0.f};
    acc = MFMA16(a0, kb0, acc);
    acc = MFMA16(a1, kb1, acc);
#pragma unroll
    for (int i = 0; i < 4; ++i) {
      const int m = mt * 16 + q * 4 + i;
      if (m < M_) runmax = fmaxf(runmax, acc[i]);
    }
  }
  for (int s2 = 1; s2 < 64; s2 <<= 1) runmax = fmaxf(runmax, __shfl_xor(runmax, s2, 64));
  __shared__ float wm[4];
  if (lane == 0) wm[wv] = runmax;
  __syncthreads();
  if (threadIdx.x == 0) {
    const float m = fmaxf(fmaxf(wm[0], wm[1]), fmaxf(wm[2], wm[3])) * NORMC;
    atomicMaxF(&kmax[bh], m);
  }
}

// ---------------- fused: td -> exp -> kp; ctx += kp x VT; ksum ----------------
__global__ __launch_bounds__(256) void ctxfused_mfma(
    const unsigned short* __restrict__ K, const unsigned short* __restrict__ VT,
    const unsigned short* __restrict__ projp, const unsigned short* __restrict__ diag_k,
    const float* __restrict__ kmaxv, float* __restrict__ ksum,
    unsigned short* __restrict__ ctxT) {
  __shared__ unsigned short kll[64][72];
  __shared__ unsigned short vtl[64][72];
  __shared__ unsigned short kpl[16][72];
  __shared__ float wks[4][16];
  const int bh = blockIdx.x, mt = blockIdx.y;
  const int wv = threadIdx.x >> 6, lane = threadIdx.x & 63;
  const int r = lane & 15, q = lane >> 4;
  const int b_ = bh >> 3, h = bh & 7;
  const int m0 = mt * 16;
  const float km = kmaxv[bh];
  const unsigned short* prow = projp + (size_t)(m0 + r) * DH_;
  const bf16x8 p0 = *(const bf16x8*)(prow + q * 8);
  const bf16x8 p1 = *(const bf16x8*)(prow + 32 + q * 8);
  const unsigned short* kbase = K + (size_t)(b_ * N_) * DIM_ + h * DH_;
  const unsigned short* vbase = VT + (size_t)bh * DH_ * N_;
  f32x4 cacc = (f32x4){0.f, 0.f, 0.f, 0.f};
  float ksa[4] = {0.f, 0.f, 0.f, 0.f};
  for (int nc = 0; nc < 64; ++nc) {
    const int n0c = nc * 64;
#pragma unroll
    for (int j = 0; j < 4; ++j) {
      const int idx = threadIdx.x + j * 256;
      const int rr = idx >> 4, c4 = (idx & 15) << 2;
      *(ushort4*)&kll[rr][c4] = *(const ushort4*)&kbase[(size_t)(n0c + rr) * DIM_ + c4];
      *(ushort4*)&vtl[rr][c4] = *(const ushort4*)&vbase[(size_t)rr * N_ + n0c + c4];
    }
    __syncthreads();
    {
      const bf16x8 kb0 = *(const bf16x8*)&kll[wv * 16 + r][q * 8];
      const bf16x8 kb1 = *(const bf16x8*)&kll[wv * 16 + r][32 + q * 8];
      f32x4 acc = (f32x4){0.f, 0.f, 0.f, 0.f};
      acc = MFMA16(p0, kb0, acc);
      acc = MFMA16(p1, kb1, acc);
      const float dgk = bfu(diag_k[bh * N_ + n0c + wv * 16 + r]);
#pragma unroll
      for (int i = 0; i < 4; ++i) {
        const int m = m0 + q * 4 + i;
        float kp = 0.f;
        if (m < M_) {
          const float arg = fminf(NORMC * acc[i] - dgk - km, 0.f);
          kp = RATIOC * (__expf(arg) + EPSK);
        }
        kpl[q * 4 + i][wv * 16 + r] = f2bf(kp);
        ksa[i] += kp;
      }
    }
    __syncthreads();
    {
      const bf16x8 a0 = *(const bf16x8*)&kpl[r][q * 8];
      const bf16x8 a1 = *(const bf16x8*)&kpl[r][32 + q * 8];
      const bf16x8 b0 = *(const bf16x8*)&vtl[wv * 16 + r][q * 8];
      const bf16x8 b1 = *(const bf16x8*)&vtl[wv * 16 + r][32 + q * 8];
      cacc = MFMA16(a0, b0, cacc);
      cacc = MFMA16(a1, b1, cacc);
    }
    __syncthreads();
  }
  {
    const int d = wv * 16 + r;
    ushort4 pk;
    pk.x = f2bf(cacc[0]); pk.y = f2bf(cacc[1]);
    pk.z = f2bf(cacc[2]); pk.w = f2bf(cacc[3]);
    *(ushort4*)&ctxT[((size_t)bh * DH_ + d) * MP2_ + m0 + q * 4] = pk;
  }
#pragma unroll
  for (int i = 0; i < 4; ++i)
    for (int s2 = 1; s2 < 16; s2 <<= 1) ksa[i] += __shfl_xor(ksa[i], s2, 64);
  if (r == 0) {
#pragma unroll
    for (int i = 0; i < 4; ++i) wks[wv][q * 4 + i] = ksa[i];
  }
  __syncthreads();
  if (threadIdx.x < 16)
    ksum[bh * MP_ + m0 + threadIdx.x] =
        wks[0][threadIdx.x] + wks[1][threadIdx.x] + wks[2][threadIdx.x] + wks[3][threadIdx.x];
}

// ---------------- fused QP + out GEMM ----------------
__global__ __launch_bounds__(256) void qpout_mfma(
    const unsigned short* __restrict__ Qb, const unsigned short* __restrict__ projp,
    const unsigned short* __restrict__ diag_q, const float* __restrict__ ksum,
    const unsigned short* __restrict__ ctxT, unsigned short* __restrict__ attn) {
  __shared__ unsigned short qps[64][296];
  __shared__ float ksums[MP_];
  __shared__ float dinvs[64];
  __shared__ float parts[4][64];
  const int bh = blockIdx.x, n0 = blockIdx.y * 64;
  const int wv = threadIdx.x >> 6, lane = threadIdx.x & 63;
  const int r = lane & 15, q = lane >> 4;
  const int b_ = bh >> 3, h = bh & 7;
  for (int i = threadIdx.x; i < MP_; i += 256) ksums[i] = ksum[bh * MP_ + i];
  for (int i = threadIdx.x; i < 64 * 24; i += 256) qps[i / 24][MP_ + (i % 24)] = 0;
  const int nrow = n0 + wv * 16 + r;
  const unsigned short* qrow = Qb + (size_t)(b_ * N_ + nrow) * DIM_ + h * DH_;
  const bf16x8 a0 = *(const bf16x8*)(qrow + q * 8);
  const bf16x8 a1 = *(const bf16x8*)(qrow + 32 + q * 8);
  float tdv[17][4];
  for (int mt = 0; mt < 17; ++mt) {
    const unsigned short* prow = projp + (size_t)(mt * 16 + r) * DH_;
    const bf16x8 p0 = *(const bf16x8*)(prow + q * 8);
    const bf16x8 p1 = *(const bf16x8*)(prow + 32 + q * 8);
    f32x4 acc = (f32x4){0.f, 0.f, 0.f, 0.f};
    acc = MFMA16(a0, p0, acc);
    acc = MFMA16(a1, p1, acc);
#pragma unroll
    for (int i = 0; i < 4; ++i) tdv[mt][i] = NORMC * acc[i];
  }
  float rmax[4];
#pragma unroll
  for (int i = 0; i < 4; ++i) {
    float v = -3e38f;
    for (int mt = 0; mt < 17; ++mt) {
      const int m = mt * 16 + r;
      if (m < M_) v = fmaxf(v, tdv[mt][i]);
    }
    rmax[i] = v;
  }
  for (int s2 = 1; s2 < 16; s2 <<= 1)
#pragma unroll
    for (int i = 0; i < 4; ++i) rmax[i] = fmaxf(rmax[i], __shfl_xor(rmax[i], s2, 64));
  float dgq[4];
#pragma unroll
  for (int i = 0; i < 4; ++i) dgq[i] = bfu(diag_q[bh * N_ + n0 + wv * 16 + q * 4 + i]);
  for (int mt = 0; mt < 17; ++mt) {
#pragma unroll
    for (int i = 0; i < 4; ++i) {
      const int m = mt * 16 + r;
      float qp = 0.f;
      if (m < M_) {
        const float arg = fminf(tdv[mt][i] - dgq[i] - rmax[i], 0.f);
        qp = RATIOC * (__expf(arg) + EPSK);
      }
      qps[wv * 16 + q * 4 + i][m] = f2bf(qp);
    }
  }
  __syncthreads();
  {
    const int row = threadIdx.x & 63, seg = threadIdx.x >> 6;
    const int ms = seg * 68, me = (ms + 68 < MP_) ? ms + 68 : MP_;
    float s = 0.f;
    for (int m = ms; m < me; ++m) s += bfu(qps[row][m]) * ksums[m];
    parts[seg][row] = s;
  }
  __syncthreads();
  if (threadIdx.x < 64) {
    const float s = parts[0][threadIdx.x] + parts[1][threadIdx.x] +
                    parts[2][threadIdx.x] + parts[3][threadIdx.x];
    dinvs[threadIdx.x] = 1.f / fmaxf(s, 1e-30f);
  }
  __syncthreads();
  f32x4 oacc[4];
#pragma unroll
  for (int i = 0; i < 4; ++i) oacc[i] = (f32x4){0.f, 0.f, 0.f, 0.f};
  const unsigned short* cbase = ctxT + (size_t)bh * DH_ * MP2_;
  for (int kc = 0; kc < 9; ++kc) {
    const bf16x8 a = *(const bf16x8*)&qps[wv * 16 + r][kc * 32 + q * 8];
#pragma unroll
    for (int dt = 0; dt < 4; ++dt) {
      const bf16x8 b = *(const bf16x8*)&cbase[(size_t)(dt * 16 + r) * MP2_ + kc * 32 + q * 8];
      oacc[dt] = MFMA16(a, b, oacc[dt]);
    }
  }
#pragma unroll
  for (int dt = 0; dt < 4; ++dt) {
    const int d = dt * 16 + r;
#pragma unroll
    for (int i = 0; i < 4; ++i) {
      const int nn = wv * 16 + q * 4 + i;
      const float o = oacc[dt][i] * dinvs[nn];
      attn[(size_t)(b_ * N_ + n0 + nn) * DIM_ + h * DH_ + d] = f2bf(o);
    }
  }
}

// ---------------- final: 128x128 LDS-staged MFMA GEMM + residual (fp32 I/O) ----------------
__global__ __launch_bounds__(256) void final_mfma(
    const unsigned short* __restrict__ attn, const unsigned short* __restrict__ Wo,
    const float* __restrict__ bo, const float* __restrict__ x,
    float* __restrict__ out) {
  __shared__ unsigned short As[128 * 64];
  __shared__ unsigned short Bs[128 * 64];
  const int t0 = blockIdx.x * 128, e0 = blockIdx.y * 128;
  const int tid = threadIdx.x;
  const int wv = tid >> 6, lane = tid & 63;
  const int r = lane & 15, q = lane >> 4;
  const int wr = (wv >> 1) * 64, wc = (wv & 1) * 64;
  f32x4 acc[4][4];
#pragma unroll
  for (int i = 0; i < 4; ++i)
#pragma unroll
    for (int j = 0; j < 4; ++j) acc[i][j] = (f32x4){0.f, 0.f, 0.f, 0.f};
  const int srow = tid >> 3, scol = (tid & 7) * 8;
  for (int k0 = 0; k0 < DIM_; k0 += 64) {
#pragma unroll
    for (int j = 0; j < 4; ++j) {
      const int rr = srow + j * 32;
      *(uint4*)&As[rr * 64 + scol] = *(const uint4*)&attn[(size_t)(t0 + rr) * DIM_ + k0 + scol];
      *(uint4*)&Bs[rr * 64 + scol] = *(const uint4*)&Wo[(size_t)(e0 + rr) * DIM_ + k0 + scol];
    }
    __syncthreads();
#pragma unroll
    for (int kc = 0; kc < 2; ++kc) {
      bf16x8 af[4], bfr[4];
#pragma unroll
      for (int rt = 0; rt < 4; ++rt)
        af[rt] = *(const bf16x8*)&As[(wr + rt * 16 + r) * 64 + kc * 32 + q * 8];
#pragma unroll
      for (int ct = 0; ct < 4; ++ct)
        bfr[ct] = *(const bf16x8*)&Bs[(wc + ct * 16 + r) * 64 + kc * 32 + q * 8];
#pragma unroll
      for (int rt = 0; rt < 4; ++rt)
#pragma unroll
        for (int ct = 0; ct < 4; ++ct)
          acc[rt][ct] = MFMA16(af[rt], bfr[ct], acc[rt][ct]);
    }
    __syncthreads();
  }
#pragma unroll
  for (int rt = 0; rt < 4; ++rt) {
#pragma unroll
    for (int ct = 0; ct < 4; ++ct) {
      const int c = e0 + wc + ct * 16 + r;
      const float bov = bo[c];
#pragma unroll
      for (int i = 0; i < 4; ++i) {
        const int t = t0 + wr + rt * 16 + q * 4 + i;
        out[(size_t)t * DIM_ + c] = acc[rt][ct][i] + bov + x[(size_t)t * DIM_ + c];
      }
    }
  }
}

extern "C" void kernel_launch(void* const* d_in, const int* in_sizes, int n_in,
                              void* d_out, int out_size, void* d_ws, size_t ws_size,
                              hipStream_t stream) {
  const float* x = (const float*)d_in[0];
  const float* Wq = (const float*)d_in[1];
  const float* Wk = (const float*)d_in[2];
  const float* Wv = (const float*)d_in[3];
  const float* Wo = (const float*)d_in[4];
  const float* bo = (const float*)d_in[5];
  const float* proj = (const float*)d_in[6];
  char* ws = (char*)d_ws;
  unsigned short* projp = (unsigned short*)(ws + PROJP_B);
  float* kmax = (float*)(ws + KMAX_B);
  float* ksum = (float*)(ws + KSUM_B);
  unsigned short* diag_q = (unsigned short*)(ws + DIAGQ_B);
  unsigned short* diag_k = (unsigned short*)(ws + DIAGK_B);
  unsigned short* ctxT = (unsigned short*)(ws + CTXT_B);
  unsigned short* xbf = (unsigned short*)(ws + XBF_B);
  unsigned short* wqb = (unsigned short*)(ws + WQ_B);
  unsigned short* wkb = (unsigned short*)(ws + WK_B);
  unsigned short* wvb = (unsigned short*)(ws + WV_B);
  unsigned short* wob = (unsigned short*)(ws + WO_B);
  unsigned short* Q = (unsigned short*)(ws + Q_B);
  unsigned short* K = (unsigned short*)(ws + K_B);
  unsigned short* VT = (unsigned short*)(ws + VT_B);
  unsigned short* attn = K;  // K dead after ctxfused_mfma
  float* out = (float*)d_out;

  cvt_kernel<<<1024, 256, 0, stream>>>(x, xbf, 8388608);
  cvt_kernel<<<128, 256, 0, stream>>>(Wq, wqb, 262144);
  cvt_kernel<<<128, 256, 0, stream>>>(Wk, wkb, 262144);
  cvt_kernel<<<128, 256, 0, stream>>>(Wv, wvb, 262144);
  cvt_kernel<<<128, 256, 0, stream>>>(Wo, wob, 262144);
  setup_kernel<<<512, 256, 0, stream>>>(proj, projp, kmax, ctxT);
  qkv_mfma<<<dim3(NT_ / 128, DIM_ / 128, 3), 256, 0, stream>>>(xbf, wqb, wkb, wvb, Q, K, VT);
  diag_kernel<<<dim3(512, 2), 256, 0, stream>>>(Q, K, diag_q, diag_k);
  kmax_mfma<<<dim3(BH_, 64), 256, 0, stream>>>(K, projp, kmax);
  ctxfused_mfma<<<dim3(BH_, 17), 256, 0, stream>>>(K, VT, projp, diag_k, kmax, ksum, ctxT);
  qpout_mfma<<<dim3(BH_, 64), 256, 0, stream>>>(Q, projp, diag_q, ksum, ctxT, attn);
  final_mfma<<<dim3(NT_ / 128, DIM_ / 128), 256, 0, stream>>>(attn, wob, bo, x, out);
}

// Round 9
// 373.920 us; speedup vs baseline: 7.3702x; 1.2226x over previous
//
#include <hip/hip_runtime.h>

#define N_ 4096
#define DIM_ 512
#define H_ 8
#define DH_ 64
#define M_ 266
#define MP_ 272      // ksum/qp live range padded to 272 (17 tiles of 16)
#define MP2_ 288     // out-GEMM K padded to 9 chunks of 32
#define MP3_ 320     // ctxfused m padded to 5 chunks of 64
#define NT_ 16384
#define BH_ 32

#define NORMC 0.3535533905932738f   // 64^-0.25
#define RATIOC 0.06131393394849658f // 266^-0.5
#define EPSK 1e-4f
#define DIAGC 0.0625f               // 0.5 * normalizer^2

// ---- ws layout (byte offsets), total ~73.6 MB ----
#define PROJP_B 0ul                        // 320*64*2 = 40960
#define KMAX_B  40960ul                    // 128
#define KSUMA_B 41088ul                    // 32*320*4 = 40960
#define CTXA_B  82048ul                    // 32*64*320*4 = 2621440
#define CTXT_B  2703488ul                  // 32*64*288*2 = 1179648
#define DIAGQ_B 3883136ul                  // 262144
#define DIAGK_B 4145280ul                  // 262144
#define XBF_B   4407424ul                  // 16777216
#define WQ_B    21184640ul                 // 524288
#define WK_B    21708928ul
#define WV_B    22233216ul
#define WO_B    22757504ul
#define Q_B     23281792ul                 // 16777216
#define K_B     40059008ul                 // 16777216 (attn aliases this)
#define VT_B    56836224ul                 // 16777216 -> ends 73613440

typedef __bf16 bf16x8 __attribute__((ext_vector_type(8)));
typedef float f32x4 __attribute__((ext_vector_type(4)));
#define MFMA16(a, b, c) __builtin_amdgcn_mfma_f32_16x16x32_bf16((a), (b), (c), 0, 0, 0)

__device__ __forceinline__ float bfu(unsigned short u) {
  union { unsigned int i; float f; } x; x.i = ((unsigned int)u) << 16; return x.f;
}
__device__ __forceinline__ unsigned short f2bf(float f) {
  union { float f; unsigned int i; } u; u.f = f;
  unsigned int r = u.i + 0x7fffu + ((u.i >> 16) & 1u);
  return (unsigned short)(r >> 16);
}
__device__ __forceinline__ void atomicMaxF(float* addr, float val) {
  int* ai = (int*)addr;
  while (true) {
    float cur = __int_as_float(*(volatile int*)ai);
    if (val <= cur) break;
    int old = atomicCAS(ai, __float_as_int(cur), __float_as_int(val));
    if (old == __float_as_int(cur)) break;
  }
}

// ---------------- fp32 -> bf16 conversion ----------------
__global__ void cvt_kernel(const float* __restrict__ src, unsigned short* __restrict__ dst, int n) {
  int i = (blockIdx.x * 256 + threadIdx.x) * 4;
  const int stride = gridDim.x * 1024;
  for (; i < n; i += stride) {
    const float4 v = *(const float4*)(src + i);
    ushort4 u;
    u.x = f2bf(v.x); u.y = f2bf(v.y); u.z = f2bf(v.z); u.w = f2bf(v.w);
    *(ushort4*)(dst + i) = u;
  }
}

// ---------------- setup: proj cvt+pad(320), kmax init, ctxa/ksuma zero ----------------
__global__ void setup_kernel(const float* __restrict__ proj,
                             unsigned short* __restrict__ projp,
                             float* __restrict__ kmax,
                             float* __restrict__ ctxa,
                             float* __restrict__ ksuma) {
  const int i = blockIdx.x * 256 + threadIdx.x;
  const int stride = gridDim.x * 256;
  for (int j = i; j < MP3_ * DH_; j += stride)
    projp[j] = (j < M_ * DH_) ? f2bf(proj[j]) : (unsigned short)0;
  for (int j = i; j < BH_; j += stride) kmax[j] = -3e38f;
  for (int j = i; j < BH_ * DH_ * MP3_; j += stride) ctxa[j] = 0.f;
  for (int j = i; j < BH_ * MP3_; j += stride) ksuma[j] = 0.f;
}

// ---------------- QKV projection: 128x128 LDS-staged MFMA GEMM ----------------
__global__ __launch_bounds__(256) void qkv_mfma(
    const unsigned short* __restrict__ x, const unsigned short* __restrict__ Wq,
    const unsigned short* __restrict__ Wk, const unsigned short* __restrict__ Wv,
    unsigned short* __restrict__ Q, unsigned short* __restrict__ K,
    unsigned short* __restrict__ VT) {
  __shared__ unsigned short As[128 * 64];
  __shared__ unsigned short Bs[128 * 64];
  const int z = blockIdx.z;
  const unsigned short* W = (z == 0) ? Wq : (z == 1) ? Wk : Wv;
  const int t0 = blockIdx.x * 128, e0 = blockIdx.y * 128;
  const int tid = threadIdx.x;
  const int wv = tid >> 6, lane = tid & 63;
  const int r = lane & 15, q = lane >> 4;
  const int wr = (wv >> 1) * 64, wc = (wv & 1) * 64;
  f32x4 acc[4][4];
#pragma unroll
  for (int i = 0; i < 4; ++i)
#pragma unroll
    for (int j = 0; j < 4; ++j) acc[i][j] = (f32x4){0.f, 0.f, 0.f, 0.f};
  const int srow = tid >> 3, scol = (tid & 7) * 8;
  for (int k0 = 0; k0 < DIM_; k0 += 64) {
#pragma unroll
    for (int j = 0; j < 4; ++j) {
      const int rr = srow + j * 32;
      *(uint4*)&As[rr * 64 + scol] = *(const uint4*)&x[(size_t)(t0 + rr) * DIM_ + k0 + scol];
      *(uint4*)&Bs[rr * 64 + scol] = *(const uint4*)&W[(size_t)(e0 + rr) * DIM_ + k0 + scol];
    }
    __syncthreads();
#pragma unroll
    for (int kc = 0; kc < 2; ++kc) {
      bf16x8 af[4], bfr[4];
#pragma unroll
      for (int rt = 0; rt < 4; ++rt)
        af[rt] = *(const bf16x8*)&As[(wr + rt * 16 + r) * 64 + kc * 32 + q * 8];
#pragma unroll
      for (int ct = 0; ct < 4; ++ct)
        bfr[ct] = *(const bf16x8*)&Bs[(wc + ct * 16 + r) * 64 + kc * 32 + q * 8];
#pragma unroll
      for (int rt = 0; rt < 4; ++rt)
#pragma unroll
        for (int ct = 0; ct < 4; ++ct)
          acc[rt][ct] = MFMA16(af[rt], bfr[ct], acc[rt][ct]);
    }
    __syncthreads();
  }
  if (z < 2) {
    unsigned short* dst = (z == 0) ? Q : K;
#pragma unroll
    for (int rt = 0; rt < 4; ++rt) {
#pragma unroll
      for (int ct = 0; ct < 4; ++ct) {
        const int e = e0 + wc + ct * 16 + r;
#pragma unroll
        for (int i = 0; i < 4; ++i) {
          const int t = t0 + wr + rt * 16 + q * 4 + i;
          dst[(size_t)t * DIM_ + e] = f2bf(acc[rt][ct][i]);
        }
      }
    }
  } else {
#pragma unroll
    for (int rt = 0; rt < 4; ++rt) {
      const int t = t0 + wr + rt * 16 + q * 4;
      const int b_ = t >> 12, n = t & (N_ - 1);
#pragma unroll
      for (int ct = 0; ct < 4; ++ct) {
        const int e = e0 + wc + ct * 16 + r;
        const int h = e >> 6, dh = e & 63;
        ushort4 pk;
        pk.x = f2bf(acc[rt][ct][0]); pk.y = f2bf(acc[rt][ct][1]);
        pk.z = f2bf(acc[rt][ct][2]); pk.w = f2bf(acc[rt][ct][3]);
        *(ushort4*)&VT[((size_t)((b_ * H_ + h) * DH_ + dh)) * N_ + n] = pk;
      }
    }
  }
}

// ---------------- diag: DIAGC * sum(t*t) per (bh, n), stored bf16 ----------------
__global__ void diag_kernel(const unsigned short* __restrict__ Q,
                            const unsigned short* __restrict__ K,
                            unsigned short* __restrict__ dq, unsigned short* __restrict__ dk) {
  const int i = blockIdx.x * 256 + threadIdx.x;
  const int bh = i >> 12, n = i & (N_ - 1);
  const int b_ = bh >> 3, h = bh & 7;
  const unsigned short* src = ((blockIdx.y == 0) ? Q : K) + (size_t)(b_ * N_ + n) * DIM_ + h * DH_;
  float s = 0.f;
#pragma unroll
  for (int c = 0; c < 16; ++c) {
    const ushort4 u = ((const ushort4*)src)[c];
    const float a = bfu(u.x), b2 = bfu(u.y), cc = bfu(u.z), d = bfu(u.w);
    s += a * a + b2 * b2 + cc * cc + d * d;
  }
  ((blockIdx.y == 0) ? dq : dk)[i] = f2bf(s * DIAGC);
}

// ---------------- kmax (MFMA) ----------------
__global__ __launch_bounds__(256) void kmax_mfma(
    const unsigned short* __restrict__ K, const unsigned short* __restrict__ projp,
    float* __restrict__ kmax) {
  const int bh = blockIdx.x, n0 = blockIdx.y * 64;
  const int wv = threadIdx.x >> 6, lane = threadIdx.x & 63;
  const int r = lane & 15, q = lane >> 4;
  const int b_ = bh >> 3, h = bh & 7;
  const int n = n0 + wv * 16 + r;
  const unsigned short* krow = K + (size_t)(b_ * N_ + n) * DIM_ + h * DH_;
  const bf16x8 kb0 = *(const bf16x8*)(krow + q * 8);
  const bf16x8 kb1 = *(const bf16x8*)(krow + 32 + q * 8);
  float runmax = -3e38f;
  for (int mt = 0; mt < 17; ++mt) {
    const unsigned short* prow = projp + (size_t)(mt * 16 + r) * DH_;
    const bf16x8 a0 = *(const bf16x8*)(prow + q * 8);
    const bf16x8 a1 = *(const bf16x8*)(prow + 32 + q * 8);
    f32x4 acc = (f32x4){0.f, 0.f, 0.f, 0.f};
    acc = MFMA16(a0, kb0, acc);
    acc = MFMA16(a1, kb1, acc);
#pragma unroll
    for (int i = 0; i < 4; ++i) {
      const int m = mt * 16 + q * 4 + i;
      if (m < M_) runmax = fmaxf(runmax, acc[i]);
    }
  }
  for (int s2 = 1; s2 < 64; s2 <<= 1) runmax = fmaxf(runmax, __shfl_xor(runmax, s2, 64));
  __shared__ float wm[4];
  if (lane == 0) wm[wv] = runmax;
  __syncthreads();
  if (threadIdx.x == 0) {
    const float m = fmaxf(fmaxf(wm[0], wm[1]), fmaxf(wm[2], wm[3])) * NORMC;
    atomicMaxF(&kmax[bh], m);
  }
}

// ---------------- fused: td -> exp -> kp; ctx += kp x VT; ksum ----------------
// grid (bh, mchunk of 64, nsplit of 4); per wave: 16 MFMAs per 64-n chunk.
__global__ __launch_bounds__(256) void ctxfused_mfma(
    const unsigned short* __restrict__ K, const unsigned short* __restrict__ VT,
    const unsigned short* __restrict__ projp, const unsigned short* __restrict__ diag_k,
    const float* __restrict__ kmaxv, float* __restrict__ ksuma,
    float* __restrict__ ctxa) {
  __shared__ unsigned short kll[64][72];
  __shared__ unsigned short vtl[64][72];
  __shared__ unsigned short kpl[64][72];
  __shared__ float dgl[64];
  const int bh = blockIdx.x, m0 = blockIdx.y * 64, nbase = blockIdx.z * 1024;
  const int tid = threadIdx.x;
  const int wv = tid >> 6, lane = tid & 63;
  const int r = lane & 15, q = lane >> 4;
  const int b_ = bh >> 3, h = bh & 7;
  const float km = kmaxv[bh];
  const unsigned short* prow = projp + (size_t)(m0 + wv * 16 + r) * DH_;
  const bf16x8 p0 = *(const bf16x8*)(prow + q * 8);
  const bf16x8 p1 = *(const bf16x8*)(prow + 32 + q * 8);
  const unsigned short* kbase = K + (size_t)(b_ * N_) * DIM_ + h * DH_;
  const unsigned short* vbase = VT + (size_t)bh * DH_ * N_;
  f32x4 cacc[4];
#pragma unroll
  for (int i = 0; i < 4; ++i) cacc[i] = (f32x4){0.f, 0.f, 0.f, 0.f};
  float ksa[4] = {0.f, 0.f, 0.f, 0.f};
  for (int nc = 0; nc < 16; ++nc) {
    const int n0c = nbase + nc * 64;
#pragma unroll
    for (int j = 0; j < 4; ++j) {
      const int idx = tid + j * 256;
      const int rr = idx >> 4, c4 = (idx & 15) << 2;
      *(ushort4*)&kll[rr][c4] = *(const ushort4*)&kbase[(size_t)(n0c + rr) * DIM_ + c4];
      *(ushort4*)&vtl[rr][c4] = *(const ushort4*)&vbase[(size_t)rr * N_ + n0c + c4];
    }
    if (tid < 16) {
      const ushort4 du = *(const ushort4*)&diag_k[bh * N_ + n0c + tid * 4];
      dgl[tid * 4 + 0] = bfu(du.x); dgl[tid * 4 + 1] = bfu(du.y);
      dgl[tid * 4 + 2] = bfu(du.z); dgl[tid * 4 + 3] = bfu(du.w);
    }
    __syncthreads();
    // td for wave's 16-m strip over all 64 n
#pragma unroll
    for (int nt = 0; nt < 4; ++nt) {
      const bf16x8 kb0 = *(const bf16x8*)&kll[nt * 16 + r][q * 8];
      const bf16x8 kb1 = *(const bf16x8*)&kll[nt * 16 + r][32 + q * 8];
      f32x4 acc = (f32x4){0.f, 0.f, 0.f, 0.f};
      acc = MFMA16(p0, kb0, acc);
      acc = MFMA16(p1, kb1, acc);
      const float dgk = dgl[nt * 16 + r];
#pragma unroll
      for (int i = 0; i < 4; ++i) {
        const int m = m0 + wv * 16 + q * 4 + i;
        float kp = 0.f;
        if (m < M_) {
          const float arg = fminf(NORMC * acc[i] - dgk - km, 0.f);
          kp = RATIOC * (__expf(arg) + EPSK);
        }
        kpl[wv * 16 + q * 4 + i][nt * 16 + r] = f2bf(kp);
        ksa[i] += kp;
      }
    }
    __syncthreads();
    // ctx: wave's 16 m x 64 d, k = 64 n
    {
      const bf16x8 a0 = *(const bf16x8*)&kpl[wv * 16 + r][q * 8];
      const bf16x8 a1 = *(const bf16x8*)&kpl[wv * 16 + r][32 + q * 8];
#pragma unroll
      for (int ct = 0; ct < 4; ++ct) {
        const bf16x8 b0 = *(const bf16x8*)&vtl[ct * 16 + r][q * 8];
        const bf16x8 b1 = *(const bf16x8*)&vtl[ct * 16 + r][32 + q * 8];
        cacc[ct] = MFMA16(a0, b0, cacc[ct]);
        cacc[ct] = MFMA16(a1, b1, cacc[ct]);
      }
    }
    __syncthreads();
  }
  // ksum: reduce over n (r lanes) then atomic
#pragma unroll
  for (int i = 0; i < 4; ++i)
    for (int s2 = 1; s2 < 16; s2 <<= 1) ksa[i] += __shfl_xor(ksa[i], s2, 64);
  if (r == 0) {
#pragma unroll
    for (int i = 0; i < 4; ++i)
      atomicAdd(&ksuma[bh * MP3_ + m0 + wv * 16 + q * 4 + i], ksa[i]);
  }
  // ctx atomics: D row = m-local (q*4+i), col = d (ct*16+r)
#pragma unroll
  for (int ct = 0; ct < 4; ++ct)
#pragma unroll
    for (int i = 0; i < 4; ++i)
      atomicAdd(&ctxa[((size_t)bh * DH_ + ct * 16 + r) * MP3_ + m0 + wv * 16 + q * 4 + i],
                cacc[ct][i]);
}

// ---------------- pack: ctxa fp32 (stride 320) -> ctxT bf16 (stride 288) ----------------
__global__ void pack_kernel(const float* __restrict__ ctxa, unsigned short* __restrict__ ctxT) {
  const int i = blockIdx.x * 256 + threadIdx.x;  // over 32*64*288
  if (i < BH_ * DH_ * MP2_) {
    const int row = i / MP2_, m = i - row * MP2_;
    ctxT[i] = f2bf(ctxa[(size_t)row * MP3_ + m]);
  }
}

// ---------------- fused QP + out GEMM ----------------
__global__ __launch_bounds__(256) void qpout_mfma(
    const unsigned short* __restrict__ Qb, const unsigned short* __restrict__ projp,
    const unsigned short* __restrict__ diag_q, const float* __restrict__ ksuma,
    const unsigned short* __restrict__ ctxT, unsigned short* __restrict__ attn) {
  __shared__ unsigned short qps[64][296];
  __shared__ float ksums[MP_];
  __shared__ float dinvs[64];
  __shared__ float parts[4][64];
  const int bh = blockIdx.x, n0 = blockIdx.y * 64;
  const int wv = threadIdx.x >> 6, lane = threadIdx.x & 63;
  const int r = lane & 15, q = lane >> 4;
  const int b_ = bh >> 3, h = bh & 7;
  for (int i = threadIdx.x; i < MP_; i += 256) ksums[i] = ksuma[bh * MP3_ + i];
  for (int i = threadIdx.x; i < 64 * 24; i += 256) qps[i / 24][MP_ + (i % 24)] = 0;
  const int nrow = n0 + wv * 16 + r;
  const unsigned short* qrow = Qb + (size_t)(b_ * N_ + nrow) * DIM_ + h * DH_;
  const bf16x8 a0 = *(const bf16x8*)(qrow + q * 8);
  const bf16x8 a1 = *(const bf16x8*)(qrow + 32 + q * 8);
  float tdv[17][4];
  for (int mt = 0; mt < 17; ++mt) {
    const unsigned short* prow = projp + (size_t)(mt * 16 + r) * DH_;
    const bf16x8 p0 = *(const bf16x8*)(prow + q * 8);
    const bf16x8 p1 = *(const bf16x8*)(prow + 32 + q * 8);
    f32x4 acc = (f32x4){0.f, 0.f, 0.f, 0.f};
    acc = MFMA16(a0, p0, acc);
    acc = MFMA16(a1, p1, acc);
#pragma unroll
    for (int i = 0; i < 4; ++i) tdv[mt][i] = NORMC * acc[i];
  }
  float rmax[4];
#pragma unroll
  for (int i = 0; i < 4; ++i) {
    float v = -3e38f;
    for (int mt = 0; mt < 17; ++mt) {
      const int m = mt * 16 + r;
      if (m < M_) v = fmaxf(v, tdv[mt][i]);
    }
    rmax[i] = v;
  }
  for (int s2 = 1; s2 < 16; s2 <<= 1)
#pragma unroll
    for (int i = 0; i < 4; ++i) rmax[i] = fmaxf(rmax[i], __shfl_xor(rmax[i], s2, 64));
  float dgq[4];
#pragma unroll
  for (int i = 0; i < 4; ++i) dgq[i] = bfu(diag_q[bh * N_ + n0 + wv * 16 + q * 4 + i]);
  for (int mt = 0; mt < 17; ++mt) {
#pragma unroll
    for (int i = 0; i < 4; ++i) {
      const int m = mt * 16 + r;
      float qp = 0.f;
      if (m < M_) {
        const float arg = fminf(tdv[mt][i] - dgq[i] - rmax[i], 0.f);
        qp = RATIOC * (__expf(arg) + EPSK);
      }
      qps[wv * 16 + q * 4 + i][m] = f2bf(qp);
    }
  }
  __syncthreads();
  {
    const int row = threadIdx.x & 63, seg = threadIdx.x >> 6;
    const int ms = seg * 68, me = (ms + 68 < MP_) ? ms + 68 : MP_;
    float s = 0.f;
    for (int m = ms; m < me; ++m) s += bfu(qps[row][m]) * ksums[m];
    parts[seg][row] = s;
  }
  __syncthreads();
  if (threadIdx.x < 64) {
    const float s = parts[0][threadIdx.x] + parts[1][threadIdx.x] +
                    parts[2][threadIdx.x] + parts[3][threadIdx.x];
    dinvs[threadIdx.x] = 1.f / fmaxf(s, 1e-30f);
  }
  __syncthreads();
  f32x4 oacc[4];
#pragma unroll
  for (int i = 0; i < 4; ++i) oacc[i] = (f32x4){0.f, 0.f, 0.f, 0.f};
  const unsigned short* cbase = ctxT + (size_t)bh * DH_ * MP2_;
  for (int kc = 0; kc < 9; ++kc) {
    const bf16x8 a = *(const bf16x8*)&qps[wv * 16 + r][kc * 32 + q * 8];
#pragma unroll
    for (int dt = 0; dt < 4; ++dt) {
      const bf16x8 b = *(const bf16x8*)&cbase[(size_t)(dt * 16 + r) * MP2_ + kc * 32 + q * 8];
      oacc[dt] = MFMA16(a, b, oacc[dt]);
    }
  }
#pragma unroll
  for (int dt = 0; dt < 4; ++dt) {
    const int d = dt * 16 + r;
#pragma unroll
    for (int i = 0; i < 4; ++i) {
      const int nn = wv * 16 + q * 4 + i;
      const float o = oacc[dt][i] * dinvs[nn];
      attn[(size_t)(b_ * N_ + n0 + nn) * DIM_ + h * DH_ + d] = f2bf(o);
    }
  }
}

// ---------------- final: 128x128 LDS-staged MFMA GEMM + residual (fp32 I/O) ----------------
__global__ __launch_bounds__(256) void final_mfma(
    const unsigned short* __restrict__ attn, const unsigned short* __restrict__ Wo,
    const float* __restrict__ bo, const float* __restrict__ x,
    float* __restrict__ out) {
  __shared__ unsigned short As[128 * 64];
  __shared__ unsigned short Bs[128 * 64];
  const int t0 = blockIdx.x * 128, e0 = blockIdx.y * 128;
  const int tid = threadIdx.x;
  const int wv = tid >> 6, lane = tid & 63;
  const int r = lane & 15, q = lane >> 4;
  const int wr = (wv >> 1) * 64, wc = (wv & 1) * 64;
  f32x4 acc[4][4];
#pragma unroll
  for (int i = 0; i < 4; ++i)
#pragma unroll
    for (int j = 0; j < 4; ++j) acc[i][j] = (f32x4){0.f, 0.f, 0.f, 0.f};
  const int srow = tid >> 3, scol = (tid & 7) * 8;
  for (int k0 = 0; k0 < DIM_; k0 += 64) {
#pragma unroll
    for (int j = 0; j < 4; ++j) {
      const int rr = srow + j * 32;
      *(uint4*)&As[rr * 64 + scol] = *(const uint4*)&attn[(size_t)(t0 + rr) * DIM_ + k0 + scol];
      *(uint4*)&Bs[rr * 64 + scol] = *(const uint4*)&Wo[(size_t)(e0 + rr) * DIM_ + k0 + scol];
    }
    __syncthreads();
#pragma unroll
    for (int kc = 0; kc < 2; ++kc) {
      bf16x8 af[4], bfr[4];
#pragma unroll
      for (int rt = 0; rt < 4; ++rt)
        af[rt] = *(const bf16x8*)&As[(wr + rt * 16 + r) * 64 + kc * 32 + q * 8];
#pragma unroll
      for (int ct = 0; ct < 4; ++ct)
        bfr[ct] = *(const bf16x8*)&Bs[(wc + ct * 16 + r) * 64 + kc * 32 + q * 8];
#pragma unroll
      for (int rt = 0; rt < 4; ++rt)
#pragma unroll
        for (int ct = 0; ct < 4; ++ct)
          acc[rt][ct] = MFMA16(af[rt], bfr[ct], acc[rt][ct]);
    }
    __syncthreads();
  }
#pragma unroll
  for (int rt = 0; rt < 4; ++rt) {
#pragma unroll
    for (int ct = 0; ct < 4; ++ct) {
      const int c = e0 + wc + ct * 16 + r;
      const float bov = bo[c];
#pragma unroll
      for (int i = 0; i < 4; ++i) {
        const int t = t0 + wr + rt * 16 + q * 4 + i;
        out[(size_t)t * DIM_ + c] = acc[rt][ct][i] + bov + x[(size_t)t * DIM_ + c];
      }
    }
  }
}

extern "C" void kernel_launch(void* const* d_in, const int* in_sizes, int n_in,
                              void* d_out, int out_size, void* d_ws, size_t ws_size,
                              hipStream_t stream) {
  const float* x = (const float*)d_in[0];
  const float* Wq = (const float*)d_in[1];
  const float* Wk = (const float*)d_in[2];
  const float* Wv = (const float*)d_in[3];
  const float* Wo = (const float*)d_in[4];
  const float* bo = (const float*)d_in[5];
  const float* proj = (const float*)d_in[6];
  char* ws = (char*)d_ws;
  unsigned short* projp = (unsigned short*)(ws + PROJP_B);
  float* kmax = (float*)(ws + KMAX_B);
  float* ksuma = (float*)(ws + KSUMA_B);
  float* ctxa = (float*)(ws + CTXA_B);
  unsigned short* ctxT = (unsigned short*)(ws + CTXT_B);
  unsigned short* diag_q = (unsigned short*)(ws + DIAGQ_B);
  unsigned short* diag_k = (unsigned short*)(ws + DIAGK_B);
  unsigned short* xbf = (unsigned short*)(ws + XBF_B);
  unsigned short* wqb = (unsigned short*)(ws + WQ_B);
  unsigned short* wkb = (unsigned short*)(ws + WK_B);
  unsigned short* wvb = (unsigned short*)(ws + WV_B);
  unsigned short* wob = (unsigned short*)(ws + WO_B);
  unsigned short* Q = (unsigned short*)(ws + Q_B);
  unsigned short* K = (unsigned short*)(ws + K_B);
  unsigned short* VT = (unsigned short*)(ws + VT_B);
  unsigned short* attn = K;  // K dead after ctxfused_mfma
  float* out = (float*)d_out;

  cvt_kernel<<<1024, 256, 0, stream>>>(x, xbf, 8388608);
  cvt_kernel<<<128, 256, 0, stream>>>(Wq, wqb, 262144);
  cvt_kernel<<<128, 256, 0, stream>>>(Wk, wkb, 262144);
  cvt_kernel<<<128, 256, 0, stream>>>(Wv, wvb, 262144);
  cvt_kernel<<<128, 256, 0, stream>>>(Wo, wob, 262144);
  setup_kernel<<<1024, 256, 0, stream>>>(proj, projp, kmax, ctxa, ksuma);
  qkv_mfma<<<dim3(NT_ / 128, DIM_ / 128, 3), 256, 0, stream>>>(xbf, wqb, wkb, wvb, Q, K, VT);
  diag_kernel<<<dim3(512, 2), 256, 0, stream>>>(Q, K, diag_q, diag_k);
  kmax_mfma<<<dim3(BH_, 64), 256, 0, stream>>>(K, projp, kmax);
  ctxfused_mfma<<<dim3(BH_, 5, 4), 256, 0, stream>>>(K, VT, projp, diag_k, kmax, ksuma, ctxa);
  pack_kernel<<<2304, 256, 0, stream>>>(ctxa, ctxT);
  qpout_mfma<<<dim3(BH_, 64), 256, 0, stream>>>(Q, projp, diag_q, ksuma, ctxT, attn);
  final_mfma<<<dim3(NT_ / 128, DIM_ / 128), 256, 0, stream>>>(attn, wob, bo, x, out);
}

// Round 10
// 352.417 us; speedup vs baseline: 7.8199x; 1.0610x over previous
//
#include <hip/hip_runtime.h>

#define N_ 4096
#define DIM_ 512
#define H_ 8
#define DH_ 64
#define M_ 266
#define MP_ 272      // ksum/qp live range padded to 272 (17 tiles of 16)
#define MP2_ 288     // out-GEMM K padded to 9 chunks of 32
#define MP3_ 320     // ctxfused m padded to 5 chunks of 64
#define NT_ 16384
#define BH_ 32

#define NORMC 0.3535533905932738f   // 64^-0.25
#define RATIOC 0.06131393394849658f // 266^-0.5
#define EPSK 1e-4f
#define DIAGC 0.0625f               // 0.5 * normalizer^2

// ---- ws layout (byte offsets), total ~73.6 MB ----
#define PROJP_B 0ul
#define KMAX_B  40960ul
#define KSUMA_B 41088ul
#define CTXA_B  82048ul
#define CTXT_B  2703488ul
#define DIAGQ_B 3883136ul
#define DIAGK_B 4145280ul
#define XBF_B   4407424ul
#define WQ_B    21184640ul
#define WK_B    21708928ul
#define WV_B    22233216ul
#define WO_B    22757504ul
#define Q_B     23281792ul
#define K_B     40059008ul
#define VT_B    56836224ul

typedef __bf16 bf16x8 __attribute__((ext_vector_type(8)));
typedef float f32x4 __attribute__((ext_vector_type(4)));
#define MFMA16(a, b, c) __builtin_amdgcn_mfma_f32_16x16x32_bf16((a), (b), (c), 0, 0, 0)

__device__ __forceinline__ float bfu(unsigned short u) {
  union { unsigned int i; float f; } x; x.i = ((unsigned int)u) << 16; return x.f;
}
__device__ __forceinline__ unsigned short f2bf(float f) {
  union { float f; unsigned int i; } u; u.f = f;
  unsigned int r = u.i + 0x7fffu + ((u.i >> 16) & 1u);
  return (unsigned short)(r >> 16);
}
__device__ __forceinline__ void atomicMaxF(float* addr, float val) {
  int* ai = (int*)addr;
  while (true) {
    float cur = __int_as_float(*(volatile int*)ai);
    if (val <= cur) break;
    int old = atomicCAS(ai, __float_as_int(cur), __float_as_int(val));
    if (old == __float_as_int(cur)) break;
  }
}

// ---------------- fp32 -> bf16 conversion ----------------
__global__ void cvt_kernel(const float* __restrict__ src, unsigned short* __restrict__ dst, int n) {
  int i = (blockIdx.x * 256 + threadIdx.x) * 4;
  const int stride = gridDim.x * 1024;
  for (; i < n; i += stride) {
    const float4 v = *(const float4*)(src + i);
    ushort4 u;
    u.x = f2bf(v.x); u.y = f2bf(v.y); u.z = f2bf(v.z); u.w = f2bf(v.w);
    *(ushort4*)(dst + i) = u;
  }
}

// ---------------- setup: proj cvt+pad(320), kmax init, ctxa/ksuma zero ----------------
__global__ void setup_kernel(const float* __restrict__ proj,
                             unsigned short* __restrict__ projp,
                             float* __restrict__ kmax,
                             float* __restrict__ ctxa,
                             float* __restrict__ ksuma) {
  const int i = blockIdx.x * 256 + threadIdx.x;
  const int stride = gridDim.x * 256;
  for (int j = i; j < MP3_ * DH_; j += stride)
    projp[j] = (j < M_ * DH_) ? f2bf(proj[j]) : (unsigned short)0;
  for (int j = i; j < BH_; j += stride) kmax[j] = -3e38f;
  for (int j = i; j < BH_ * DH_ * MP3_; j += stride) ctxa[j] = 0.f;
  for (int j = i; j < BH_ * MP3_; j += stride) ksuma[j] = 0.f;
}

// ---------------- QKV projection: 128x128 LDS-staged MFMA GEMM ----------------
__global__ __launch_bounds__(256) void qkv_mfma(
    const unsigned short* __restrict__ x, const unsigned short* __restrict__ Wq,
    const unsigned short* __restrict__ Wk, const unsigned short* __restrict__ Wv,
    unsigned short* __restrict__ Q, unsigned short* __restrict__ K,
    unsigned short* __restrict__ VT) {
  __shared__ unsigned short As[128 * 64];
  __shared__ unsigned short Bs[128 * 64];
  const int z = blockIdx.z;
  const unsigned short* W = (z == 0) ? Wq : (z == 1) ? Wk : Wv;
  const int t0 = blockIdx.x * 128, e0 = blockIdx.y * 128;
  const int tid = threadIdx.x;
  const int wv = tid >> 6, lane = tid & 63;
  const int r = lane & 15, q = lane >> 4;
  const int wr = (wv >> 1) * 64, wc = (wv & 1) * 64;
  f32x4 acc[4][4];
#pragma unroll
  for (int i = 0; i < 4; ++i)
#pragma unroll
    for (int j = 0; j < 4; ++j) acc[i][j] = (f32x4){0.f, 0.f, 0.f, 0.f};
  const int srow = tid >> 3, scol = (tid & 7) * 8;
  for (int k0 = 0; k0 < DIM_; k0 += 64) {
#pragma unroll
    for (int j = 0; j < 4; ++j) {
      const int rr = srow + j * 32;
      *(uint4*)&As[rr * 64 + scol] = *(const uint4*)&x[(size_t)(t0 + rr) * DIM_ + k0 + scol];
      *(uint4*)&Bs[rr * 64 + scol] = *(const uint4*)&W[(size_t)(e0 + rr) * DIM_ + k0 + scol];
    }
    __syncthreads();
#pragma unroll
    for (int kc = 0; kc < 2; ++kc) {
      bf16x8 af[4], bfr[4];
#pragma unroll
      for (int rt = 0; rt < 4; ++rt)
        af[rt] = *(const bf16x8*)&As[(wr + rt * 16 + r) * 64 + kc * 32 + q * 8];
#pragma unroll
      for (int ct = 0; ct < 4; ++ct)
        bfr[ct] = *(const bf16x8*)&Bs[(wc + ct * 16 + r) * 64 + kc * 32 + q * 8];
#pragma unroll
      for (int rt = 0; rt < 4; ++rt)
#pragma unroll
        for (int ct = 0; ct < 4; ++ct)
          acc[rt][ct] = MFMA16(af[rt], bfr[ct], acc[rt][ct]);
    }
    __syncthreads();
  }
  if (z < 2) {
    unsigned short* dst = (z == 0) ? Q : K;
#pragma unroll
    for (int rt = 0; rt < 4; ++rt) {
#pragma unroll
      for (int ct = 0; ct < 4; ++ct) {
        const int e = e0 + wc + ct * 16 + r;
#pragma unroll
        for (int i = 0; i < 4; ++i) {
          const int t = t0 + wr + rt * 16 + q * 4 + i;
          dst[(size_t)t * DIM_ + e] = f2bf(acc[rt][ct][i]);
        }
      }
    }
  } else {
#pragma unroll
    for (int rt = 0; rt < 4; ++rt) {
      const int t = t0 + wr + rt * 16 + q * 4;
      const int b_ = t >> 12, n = t & (N_ - 1);
#pragma unroll
      for (int ct = 0; ct < 4; ++ct) {
        const int e = e0 + wc + ct * 16 + r;
        const int h = e >> 6, dh = e & 63;
        ushort4 pk;
        pk.x = f2bf(acc[rt][ct][0]); pk.y = f2bf(acc[rt][ct][1]);
        pk.z = f2bf(acc[rt][ct][2]); pk.w = f2bf(acc[rt][ct][3]);
        *(ushort4*)&VT[((size_t)((b_ * H_ + h) * DH_ + dh)) * N_ + n] = pk;
      }
    }
  }
}

// ---------------- diag: DIAGC * sum(t*t) per (bh, n), stored bf16 ----------------
__global__ void diag_kernel(const unsigned short* __restrict__ Q,
                            const unsigned short* __restrict__ K,
                            unsigned short* __restrict__ dq, unsigned short* __restrict__ dk) {
  const int i = blockIdx.x * 256 + threadIdx.x;
  const int bh = i >> 12, n = i & (N_ - 1);
  const int b_ = bh >> 3, h = bh & 7;
  const unsigned short* src = ((blockIdx.y == 0) ? Q : K) + (size_t)(b_ * N_ + n) * DIM_ + h * DH_;
  float s = 0.f;
#pragma unroll
  for (int c = 0; c < 16; ++c) {
    const ushort4 u = ((const ushort4*)src)[c];
    const float a = bfu(u.x), b2 = bfu(u.y), cc = bfu(u.z), d = bfu(u.w);
    s += a * a + b2 * b2 + cc * cc + d * d;
  }
  ((blockIdx.y == 0) ? dq : dk)[i] = f2bf(s * DIAGC);
}

// ---------------- kmax (MFMA): 2 n-strips per wave, 68 MFMAs/wave ----------------
__global__ __launch_bounds__(256) void kmax_mfma(
    const unsigned short* __restrict__ K, const unsigned short* __restrict__ projp,
    float* __restrict__ kmax) {
  const int bh = blockIdx.x, n0 = blockIdx.y * 128;
  const int wv = threadIdx.x >> 6, lane = threadIdx.x & 63;
  const int r = lane & 15, q = lane >> 4;
  const int b_ = bh >> 3, h = bh & 7;
  bf16x8 kb[2][2];
#pragma unroll
  for (int nt = 0; nt < 2; ++nt) {
    const int n = n0 + wv * 32 + nt * 16 + r;
    const unsigned short* krow = K + (size_t)(b_ * N_ + n) * DIM_ + h * DH_;
    kb[nt][0] = *(const bf16x8*)(krow + q * 8);
    kb[nt][1] = *(const bf16x8*)(krow + 32 + q * 8);
  }
  float runmax = -3e38f;
  for (int mt = 0; mt < 17; ++mt) {
    const unsigned short* prow = projp + (size_t)(mt * 16 + r) * DH_;
    const bf16x8 a0 = *(const bf16x8*)(prow + q * 8);
    const bf16x8 a1 = *(const bf16x8*)(prow + 32 + q * 8);
#pragma unroll
    for (int nt = 0; nt < 2; ++nt) {
      f32x4 acc = (f32x4){0.f, 0.f, 0.f, 0.f};
      acc = MFMA16(a0, kb[nt][0], acc);
      acc = MFMA16(a1, kb[nt][1], acc);
#pragma unroll
      for (int i = 0; i < 4; ++i) {
        const int m = mt * 16 + q * 4 + i;
        if (m < M_) runmax = fmaxf(runmax, acc[i]);
      }
    }
  }
  for (int s2 = 1; s2 < 64; s2 <<= 1) runmax = fmaxf(runmax, __shfl_xor(runmax, s2, 64));
  __shared__ float wm[4];
  if (lane == 0) wm[wv] = runmax;
  __syncthreads();
  if (threadIdx.x == 0) {
    const float m = fmaxf(fmaxf(wm[0], wm[1]), fmaxf(wm[2], wm[3])) * NORMC;
    atomicMaxF(&kmax[bh], m);
  }
}

// ---------------- fused: td -> exp -> kp; ctx += kp x VT; ksum ----------------
__global__ __launch_bounds__(256) void ctxfused_mfma(
    const unsigned short* __restrict__ K, const unsigned short* __restrict__ VT,
    const unsigned short* __restrict__ projp, const unsigned short* __restrict__ diag_k,
    const float* __restrict__ kmaxv, float* __restrict__ ksuma,
    float* __restrict__ ctxa) {
  __shared__ unsigned short kll[64][72];
  __shared__ unsigned short vtl[64][72];
  __shared__ unsigned short kpl[64][72];
  __shared__ float dgl[64];
  const int bh = blockIdx.x, m0 = blockIdx.y * 64, nbase = blockIdx.z * 1024;
  const int tid = threadIdx.x;
  const int wv = tid >> 6, lane = tid & 63;
  const int r = lane & 15, q = lane >> 4;
  const int b_ = bh >> 3, h = bh & 7;
  const float km = kmaxv[bh];
  const unsigned short* prow = projp + (size_t)(m0 + wv * 16 + r) * DH_;
  const bf16x8 p0 = *(const bf16x8*)(prow + q * 8);
  const bf16x8 p1 = *(const bf16x8*)(prow + 32 + q * 8);
  const unsigned short* kbase = K + (size_t)(b_ * N_) * DIM_ + h * DH_;
  const unsigned short* vbase = VT + (size_t)bh * DH_ * N_;
  f32x4 cacc[4];
#pragma unroll
  for (int i = 0; i < 4; ++i) cacc[i] = (f32x4){0.f, 0.f, 0.f, 0.f};
  float ksa[4] = {0.f, 0.f, 0.f, 0.f};
  for (int nc = 0; nc < 16; ++nc) {
    const int n0c = nbase + nc * 64;
#pragma unroll
    for (int j = 0; j < 4; ++j) {
      const int idx = tid + j * 256;
      const int rr = idx >> 4, c4 = (idx & 15) << 2;
      *(ushort4*)&kll[rr][c4] = *(const ushort4*)&kbase[(size_t)(n0c + rr) * DIM_ + c4];
      *(ushort4*)&vtl[rr][c4] = *(const ushort4*)&vbase[(size_t)rr * N_ + n0c + c4];
    }
    if (tid < 16) {
      const ushort4 du = *(const ushort4*)&diag_k[bh * N_ + n0c + tid * 4];
      dgl[tid * 4 + 0] = bfu(du.x); dgl[tid * 4 + 1] = bfu(du.y);
      dgl[tid * 4 + 2] = bfu(du.z); dgl[tid * 4 + 3] = bfu(du.w);
    }
    __syncthreads();
#pragma unroll
    for (int nt = 0; nt < 4; ++nt) {
      const bf16x8 kb0 = *(const bf16x8*)&kll[nt * 16 + r][q * 8];
      const bf16x8 kb1 = *(const bf16x8*)&kll[nt * 16 + r][32 + q * 8];
      f32x4 acc = (f32x4){0.f, 0.f, 0.f, 0.f};
      acc = MFMA16(p0, kb0, acc);
      acc = MFMA16(p1, kb1, acc);
      const float dgk = dgl[nt * 16 + r];
#pragma unroll
      for (int i = 0; i < 4; ++i) {
        const int m = m0 + wv * 16 + q * 4 + i;
        float kp = 0.f;
        if (m < M_) {
          const float arg = fminf(NORMC * acc[i] - dgk - km, 0.f);
          kp = RATIOC * (__expf(arg) + EPSK);
        }
        kpl[wv * 16 + q * 4 + i][nt * 16 + r] = f2bf(kp);
        ksa[i] += kp;
      }
    }
    __syncthreads();
    {
      const bf16x8 a0 = *(const bf16x8*)&kpl[wv * 16 + r][q * 8];
      const bf16x8 a1 = *(const bf16x8*)&kpl[wv * 16 + r][32 + q * 8];
#pragma unroll
      for (int ct = 0; ct < 4; ++ct) {
        const bf16x8 b0 = *(const bf16x8*)&vtl[ct * 16 + r][q * 8];
        const bf16x8 b1 = *(const bf16x8*)&vtl[ct * 16 + r][32 + q * 8];
        cacc[ct] = MFMA16(a0, b0, cacc[ct]);
        cacc[ct] = MFMA16(a1, b1, cacc[ct]);
      }
    }
    __syncthreads();
  }
#pragma unroll
  for (int i = 0; i < 4; ++i)
    for (int s2 = 1; s2 < 16; s2 <<= 1) ksa[i] += __shfl_xor(ksa[i], s2, 64);
  if (r == 0) {
#pragma unroll
    for (int i = 0; i < 4; ++i)
      atomicAdd(&ksuma[bh * MP3_ + m0 + wv * 16 + q * 4 + i], ksa[i]);
  }
#pragma unroll
  for (int ct = 0; ct < 4; ++ct)
#pragma unroll
    for (int i = 0; i < 4; ++i)
      atomicAdd(&ctxa[((size_t)bh * DH_ + ct * 16 + r) * MP3_ + m0 + wv * 16 + q * 4 + i],
                cacc[ct][i]);
}

// ---------------- pack: ctxa fp32 (stride 320) -> ctxT bf16 (stride 288) ----------------
__global__ void pack_kernel(const float* __restrict__ ctxa, unsigned short* __restrict__ ctxT) {
  const int i = blockIdx.x * 256 + threadIdx.x;
  if (i < BH_ * DH_ * MP2_) {
    const int row = i / MP2_, m = i - row * MP2_;
    ctxT[i] = f2bf(ctxa[(size_t)row * MP3_ + m]);
  }
}

// ---------------- fused QP + out GEMM (2 barriers, register dinv) ----------------
__global__ __launch_bounds__(256) void qpout_mfma(
    const unsigned short* __restrict__ Qb, const unsigned short* __restrict__ projp,
    const unsigned short* __restrict__ diag_q, const float* __restrict__ ksuma,
    const unsigned short* __restrict__ ctxT, unsigned short* __restrict__ attn) {
  __shared__ unsigned short qps[64][296];
  __shared__ float ksums[MP_];
  const int bh = blockIdx.x, n0 = blockIdx.y * 64;
  const int wv = threadIdx.x >> 6, lane = threadIdx.x & 63;
  const int r = lane & 15, q = lane >> 4;
  const int b_ = bh >> 3, h = bh & 7;
  for (int i = threadIdx.x; i < MP_; i += 256) ksums[i] = ksuma[bh * MP3_ + i];
  {  // zero pad cols 272..295 (phase C reads through col 287)
    const int row = threadIdx.x & 63, c0 = MP_ + (threadIdx.x >> 6) * 6;
#pragma unroll
    for (int j = 0; j < 6; ++j) qps[row][c0 + j] = 0;
  }
  __syncthreads();
  // Phase A: QP GEMM; A = Q rows (n), B = proj rows (m)
  const int nrow = n0 + wv * 16 + r;
  const unsigned short* qrow = Qb + (size_t)(b_ * N_ + nrow) * DIM_ + h * DH_;
  const bf16x8 a0 = *(const bf16x8*)(qrow + q * 8);
  const bf16x8 a1 = *(const bf16x8*)(qrow + 32 + q * 8);
  float tdv[17][4];
  for (int mt = 0; mt < 17; ++mt) {
    const unsigned short* prow = projp + (size_t)(mt * 16 + r) * DH_;
    const bf16x8 p0 = *(const bf16x8*)(prow + q * 8);
    const bf16x8 p1 = *(const bf16x8*)(prow + 32 + q * 8);
    f32x4 acc = (f32x4){0.f, 0.f, 0.f, 0.f};
    acc = MFMA16(a0, p0, acc);
    acc = MFMA16(a1, p1, acc);
#pragma unroll
    for (int i = 0; i < 4; ++i) tdv[mt][i] = NORMC * acc[i];
  }
  // per-row max over m (lane covers m = mt*16 + r -> butterfly over r bits)
  float rmax[4];
#pragma unroll
  for (int i = 0; i < 4; ++i) {
    float v = -3e38f;
    for (int mt = 0; mt < 17; ++mt) {
      const int m = mt * 16 + r;
      if (m < M_) v = fmaxf(v, tdv[mt][i]);
    }
    rmax[i] = v;
  }
  for (int s2 = 1; s2 < 16; s2 <<= 1)
#pragma unroll
    for (int i = 0; i < 4; ++i) rmax[i] = fmaxf(rmax[i], __shfl_xor(rmax[i], s2, 64));
  float dgq[4];
#pragma unroll
  for (int i = 0; i < 4; ++i) dgq[i] = bfu(diag_q[bh * N_ + n0 + wv * 16 + q * 4 + i]);
  // exp, write qps, accumulate denominator partials in registers
  float part[4] = {0.f, 0.f, 0.f, 0.f};
  for (int mt = 0; mt < 17; ++mt) {
#pragma unroll
    for (int i = 0; i < 4; ++i) {
      const int m = mt * 16 + r;
      unsigned short qb = 0;
      if (m < M_) {
        const float arg = fminf(tdv[mt][i] - dgq[i] - rmax[i], 0.f);
        qb = f2bf(RATIOC * (__expf(arg) + EPSK));
      }
      qps[wv * 16 + q * 4 + i][m] = qb;
      part[i] += bfu(qb) * ksums[m];
    }
  }
  // butterfly over r bits -> full denominator for rows q*4+i (stays in this lane group)
  for (int s2 = 1; s2 < 16; s2 <<= 1)
#pragma unroll
    for (int i = 0; i < 4; ++i) part[i] += __shfl_xor(part[i], s2, 64);
  float dinv[4];
#pragma unroll
  for (int i = 0; i < 4; ++i) dinv[i] = 1.f / fmaxf(part[i], 1e-30f);
  __syncthreads();
  // Phase C: out = qp . ctxT  (K = 288)
  f32x4 oacc[4];
#pragma unroll
  for (int i = 0; i < 4; ++i) oacc[i] = (f32x4){0.f, 0.f, 0.f, 0.f};
  const unsigned short* cbase = ctxT + (size_t)bh * DH_ * MP2_;
  for (int kc = 0; kc < 9; ++kc) {
    const bf16x8 a = *(const bf16x8*)&qps[wv * 16 + r][kc * 32 + q * 8];
#pragma unroll
    for (int dt = 0; dt < 4; ++dt) {
      const bf16x8 b = *(const bf16x8*)&cbase[(size_t)(dt * 16 + r) * MP2_ + kc * 32 + q * 8];
      oacc[dt] = MFMA16(a, b, oacc[dt]);
    }
  }
#pragma unroll
  for (int dt = 0; dt < 4; ++dt) {
    const int d = dt * 16 + r;
#pragma unroll
    for (int i = 0; i < 4; ++i) {
      const int nn = wv * 16 + q * 4 + i;
      const float o = oacc[dt][i] * dinv[i];
      attn[(size_t)(b_ * N_ + n0 + nn) * DIM_ + h * DH_ + d] = f2bf(o);
    }
  }
}

// ---------------- final: 128x128 LDS-staged MFMA GEMM + residual (fp32 I/O) ----------------
__global__ __launch_bounds__(256) void final_mfma(
    const unsigned short* __restrict__ attn, const unsigned short* __restrict__ Wo,
    const float* __restrict__ bo, const float* __restrict__ x,
    float* __restrict__ out) {
  __shared__ unsigned short As[128 * 64];
  __shared__ unsigned short Bs[128 * 64];
  const int t0 = blockIdx.x * 128, e0 = blockIdx.y * 128;
  const int tid = threadIdx.x;
  const int wv = tid >> 6, lane = tid & 63;
  const int r = lane & 15, q = lane >> 4;
  const int wr = (wv >> 1) * 64, wc = (wv & 1) * 64;
  f32x4 acc[4][4];
#pragma unroll
  for (int i = 0; i < 4; ++i)
#pragma unroll
    for (int j = 0; j < 4; ++j) acc[i][j] = (f32x4){0.f, 0.f, 0.f, 0.f};
  const int srow = tid >> 3, scol = (tid & 7) * 8;
  for (int k0 = 0; k0 < DIM_; k0 += 64) {
#pragma unroll
    for (int j = 0; j < 4; ++j) {
      const int rr = srow + j * 32;
      *(uint4*)&As[rr * 64 + scol] = *(const uint4*)&attn[(size_t)(t0 + rr) * DIM_ + k0 + scol];
      *(uint4*)&Bs[rr * 64 + scol] = *(const uint4*)&Wo[(size_t)(e0 + rr) * DIM_ + k0 + scol];
    }
    __syncthreads();
#pragma unroll
    for (int kc = 0; kc < 2; ++kc) {
      bf16x8 af[4], bfr[4];
#pragma unroll
      for (int rt = 0; rt < 4; ++rt)
        af[rt] = *(const bf16x8*)&As[(wr + rt * 16 + r) * 64 + kc * 32 + q * 8];
#pragma unroll
      for (int ct = 0; ct < 4; ++ct)
        bfr[ct] = *(const bf16x8*)&Bs[(wc + ct * 16 + r) * 64 + kc * 32 + q * 8];
#pragma unroll
      for (int rt = 0; rt < 4; ++rt)
#pragma unroll
        for (int ct = 0; ct < 4; ++ct)
          acc[rt][ct] = MFMA16(af[rt], bfr[ct], acc[rt][ct]);
    }
    __syncthreads();
  }
#pragma unroll
  for (int rt = 0; rt < 4; ++rt) {
#pragma unroll
    for (int ct = 0; ct < 4; ++ct) {
      const int c = e0 + wc + ct * 16 + r;
      const float bov = bo[c];
#pragma unroll
      for (int i = 0; i < 4; ++i) {
        const int t = t0 + wr + rt * 16 + q * 4 + i;
        out[(size_t)t * DIM_ + c] = acc[rt][ct][i] + bov + x[(size_t)t * DIM_ + c];
      }
    }
  }
}

extern "C" void kernel_launch(void* const* d_in, const int* in_sizes, int n_in,
                              void* d_out, int out_size, void* d_ws, size_t ws_size,
                              hipStream_t stream) {
  const float* x = (const float*)d_in[0];
  const float* Wq = (const float*)d_in[1];
  const float* Wk = (const float*)d_in[2];
  const float* Wv = (const float*)d_in[3];
  const float* Wo = (const float*)d_in[4];
  const float* bo = (const float*)d_in[5];
  const float* proj = (const float*)d_in[6];
  char* ws = (char*)d_ws;
  unsigned short* projp = (unsigned short*)(ws + PROJP_B);
  float* kmax = (float*)(ws + KMAX_B);
  float* ksuma = (float*)(ws + KSUMA_B);
  float* ctxa = (float*)(ws + CTXA_B);
  unsigned short* ctxT = (unsigned short*)(ws + CTXT_B);
  unsigned short* diag_q = (unsigned short*)(ws + DIAGQ_B);
  unsigned short* diag_k = (unsigned short*)(ws + DIAGK_B);
  unsigned short* xbf = (unsigned short*)(ws + XBF_B);
  unsigned short* wqb = (unsigned short*)(ws + WQ_B);
  unsigned short* wkb = (unsigned short*)(ws + WK_B);
  unsigned short* wvb = (unsigned short*)(ws + WV_B);
  unsigned short* wob = (unsigned short*)(ws + WO_B);
  unsigned short* Q = (unsigned short*)(ws + Q_B);
  unsigned short* K = (unsigned short*)(ws + K_B);
  unsigned short* VT = (unsigned short*)(ws + VT_B);
  unsigned short* attn = K;  // K dead after ctxfused_mfma
  float* out = (float*)d_out;

  cvt_kernel<<<1024, 256, 0, stream>>>(x, xbf, 8388608);
  cvt_kernel<<<128, 256, 0, stream>>>(Wq, wqb, 262144);
  cvt_kernel<<<128, 256, 0, stream>>>(Wk, wkb, 262144);
  cvt_kernel<<<128, 256, 0, stream>>>(Wv, wvb, 262144);
  cvt_kernel<<<128, 256, 0, stream>>>(Wo, wob, 262144);
  setup_kernel<<<1024, 256, 0, stream>>>(proj, projp, kmax, ctxa, ksuma);
  qkv_mfma<<<dim3(NT_ / 128, DIM_ / 128, 3), 256, 0, stream>>>(xbf, wqb, wkb, wvb, Q, K, VT);
  diag_kernel<<<dim3(512, 2), 256, 0, stream>>>(Q, K, diag_q, diag_k);
  kmax_mfma<<<dim3(BH_, 32), 256, 0, stream>>>(K, projp, kmax);
  ctxfused_mfma<<<dim3(BH_, 5, 4), 256, 0, stream>>>(K, VT, projp, diag_k, kmax, ksuma, ctxa);
  pack_kernel<<<2304, 256, 0, stream>>>(ctxa, ctxT);
  qpout_mfma<<<dim3(BH_, 64), 256, 0, stream>>>(Q, projp, diag_q, ksuma, ctxT, attn);
  final_mfma<<<dim3(NT_ / 128, DIM_ / 128), 256, 0, stream>>>(attn, wob, bo, x, out);
}